// Round 6
// baseline (1576.924 us; speedup 1.0000x reference)
//
#include <hip/hip_runtime.h>
#include <math.h>

#define B_ 64
#define N_ 29
#define E_ 812
#define L_ 9
#define H_ 256
#define FA_ 5
#define BN_ (B_*N_)   // 1856
#define BE_ (B_*E_)   // 51968
#define DEG_ 28
#define SCALE_ 15.0f

typedef __attribute__((ext_vector_type(8))) short bf16x8;
typedef __attribute__((ext_vector_type(4))) float f32x4;

__device__ __forceinline__ float sigmoidf_(float v){ return 1.0f/(1.0f+expf(-v)); }
__device__ __forceinline__ float siluf_(float v){ return v/(1.0f+expf(-v)); }

// bf16 round-to-nearest-even conversion + back
__device__ __forceinline__ ushort f2bf(float f){
    uint u = __float_as_uint(f);
    u += 0x7fffu + ((u>>16)&1u);
    return (ushort)(u>>16);
}
__device__ __forceinline__ float bf2f(ushort h){ return __uint_as_float(((uint)h)<<16); }

// ---------------- init ----------------
__global__ void k_init_h(const float* __restrict__ h_in, const float* __restrict__ t,
                         const float* __restrict__ win_w, const float* __restrict__ win_b,
                         float* __restrict__ h)
{
    int node = blockIdx.x; int c = threadIdx.x;
    float in[6];
    #pragma unroll
    for (int k=0;k<FA_;k++) in[k] = h_in[node*FA_+k];
    in[5] = t[node];
    float acc = win_b[c];
    #pragma unroll
    for (int k=0;k<6;k++) acc += in[k]*win_w[k*H_+c];
    h[(size_t)node*H_+c] = acc;
}

__global__ void k_init_xa(const float* __restrict__ x_in, const int* __restrict__ eidx,
                          const float* __restrict__ emask, float* __restrict__ x, float* __restrict__ a)
{
    int gid = blockIdx.x*256 + threadIdx.x;
    if (gid < BN_*3) x[gid] = x_in[gid];
    if (gid < BE_) {
        int b = gid / E_;
        int ii = eidx[2*gid], jj = eidx[2*gid+1];
        const float* xi = x_in + (size_t)(b*N_+ii)*3;
        const float* xj = x_in + (size_t)(b*N_+jj)*3;
        float dx = xi[0]-xj[0], dy = xi[1]-xj[1], dz = xi[2]-xj[2];
        a[gid] = sqrtf(dx*dx+dy*dy+dz*dz) * emask[gid];
    }
}

// ---------------- W fragmentization: row-major [K=256][N=256] fp32 -> MFMA B-frag bf16 hi/lo ----------------
// Layout per (layer,pass): hi plane [ks(8)][ct(16)][lane(64)][8] (65536 bf16), lo plane at +65536.
// Fragment semantic: lane holds B[k = ks*32 + (lane>>4)*8 + j][col = ct*16 + (lane&15)], j=0..7.
__global__ void k_wprep(const float* __restrict__ xw2, const float* __restrict__ ew2,
                        ushort* __restrict__ WfU, ushort* __restrict__ WfM)
{
    int gid = blockIdx.x*256 + threadIdx.x;
    if (gid >= L_*2*8192) return;
    int lane = gid & 63;
    int rest = gid >> 6;
    int ct = rest & 15; rest >>= 4;
    int ks = rest & 7;  rest >>= 3;
    int p  = rest & 1;  int l = rest >> 1;
    const float* src = (p ? ew2 : xw2) + (size_t)l*H_*H_;
    ushort* dst = (p ? WfM : WfU) + (size_t)l*131072;
    int g = lane>>4, li = lane&15;
    int col = ct*16 + li;
    int kb  = ks*32 + g*8;
    size_t fo = ((size_t)(ks*16+ct)*64 + lane)*8;
    ushort* dh = dst + fo;
    ushort* dl = dst + 65536 + fo;
    #pragma unroll
    for (int j=0;j<8;j++){
        float v = src[(size_t)(kb+j)*H_ + col];
        ushort h = f2bf(v);
        dh[j] = h;
        dl[j] = f2bf(v - bf2f(h));
    }
}

// ---------------- generic tiled fp32 GEMM (node-side) ----------------
struct GArg { const float* A; const float* Bw; const float* bias; const float* add; const float* rmask; float* C; };
struct GArgs { GArg g[6]; };

template<int ACT>
__global__ __launch_bounds__(256)
void k_gemm64(GArgs args, int M, int Kdim)
{
    const GArg ga = args.g[blockIdx.z];
    __shared__ float As[16*68];
    __shared__ float Bs[16*68];
    const int tid = threadIdx.x;
    const int row0 = blockIdx.x*64;
    const int col0 = blockIdx.y*64;
    const int ty = tid>>4, tx = tid&15;
    const int am = tid>>2, ak = (tid&3)<<2;
    const int bk = tid>>4, bn = (tid&15)<<2;
    float acc[4][4] = {};
    const float* Ap = ga.A + (size_t)min(row0+am, M-1)*Kdim + ak;
    const float* Bp = ga.Bw + (size_t)bk*H_ + col0 + bn;
    for (int k0=0; k0<Kdim; k0+=16) {
        float4 av = *(const float4*)(Ap + k0);
        float4 bv = *(const float4*)(Bp + (size_t)k0*H_);
        __syncthreads();
        As[(ak+0)*68+am]=av.x; As[(ak+1)*68+am]=av.y; As[(ak+2)*68+am]=av.z; As[(ak+3)*68+am]=av.w;
        *(float4*)&Bs[bk*68+bn] = bv;
        __syncthreads();
        #pragma unroll
        for (int k=0;k<16;k++) {
            float4 a4 = *(const float4*)&As[k*68 + (ty<<2)];
            float4 b4 = *(const float4*)&Bs[k*68 + (tx<<2)];
            float aa[4]={a4.x,a4.y,a4.z,a4.w};
            float bb[4]={b4.x,b4.y,b4.z,b4.w};
            #pragma unroll
            for (int i=0;i<4;i++)
                #pragma unroll
                for (int j=0;j<4;j++)
                    acc[i][j] = fmaf(aa[i], bb[j], acc[i][j]);
        }
    }
    const int r0 = row0 + (ty<<2);
    const int c0 = col0 + (tx<<2);
    float4 bias4 = make_float4(0.f,0.f,0.f,0.f);
    if (ga.bias) bias4 = *(const float4*)(ga.bias + c0);
    #pragma unroll
    for (int i=0;i<4;i++) {
        int r = r0+i;
        if (r >= M) break;
        float v0=acc[i][0]+bias4.x, v1=acc[i][1]+bias4.y, v2=acc[i][2]+bias4.z, v3=acc[i][3]+bias4.w;
        if (ga.add) {
            float4 ad = *(const float4*)(ga.add + (size_t)r*H_ + c0);
            v0+=ad.x; v1+=ad.y; v2+=ad.z; v3+=ad.w;
        }
        if (ACT==1) { v0=siluf_(v0); v1=siluf_(v1); v2=siluf_(v2); v3=siluf_(v3); }
        if (ga.rmask) { float mv = ga.rmask[r]; v0*=mv; v1*=mv; v2*=mv; v3*=mv; }
        *(float4*)(ga.C + (size_t)r*H_ + c0) = make_float4(v0,v1,v2,v3);
    }
}

// ---------------- edge MLP layer-1 assembly, emits A-planes in MFMA FRAGMENT order ----------------
// Band = node PAIR (56 real edges, rows 56..63 zero-padded).
// Plane layout (per hi/lo plane): [pb][ks(8)][rt(4)][lane(64)][8] ushorts (16384 per band).
// Fragment: lane(g=lane>>4, li=lane&15) holds A[row = rt*16+li][k = ks*32+g*8+j], j=0..7,
// where row r < 56 maps to global edge (g0+2*pb)*28 + r.
__global__ void k_edge_mlp1(const float* __restrict__ XHi, const float* __restrict__ XHj,
                            const float* __restrict__ EHi, const float* __restrict__ EHj,
                            const float* __restrict__ x, const float* __restrict__ a,
                            const int* __restrict__ eidx, const float* __restrict__ emask,
                            const float* __restrict__ xw512, const float* __restrict__ xw513, const float* __restrict__ xb1,
                            const float* __restrict__ ew512, const float* __restrict__ ew513, const float* __restrict__ eb1,
                            ushort* __restrict__ u1h, ushort* __restrict__ u1l,
                            ushort* __restrict__ m1h, ushort* __restrict__ m1l,
                            int g0, int npairs)
{
    int gid = blockIdx.x*256 + threadIdx.x;
    if (gid >= npairs*2048) return;
    int lane = gid & 63;
    int rest = gid >> 6;
    int rt = rest & 3; rest >>= 2;
    int ks = rest & 7; rest >>= 3;
    int pb = rest;
    int li = lane & 15, g = lane >> 4;
    int r = rt*16 + li;
    int kb  = ks*32 + g*8;
    size_t fo = ((size_t)((pb*8+ks)*4+rt)*64 + lane)*8;

    if (r >= 2*DEG_) {   // pad rows 56..63
        ushort4 z4 = make_ushort4(0,0,0,0);
        *(ushort4*)(u1h+fo)=z4; *(ushort4*)(u1h+fo+4)=z4;
        *(ushort4*)(u1l+fo)=z4; *(ushort4*)(u1l+fo+4)=z4;
        *(ushort4*)(m1h+fo)=z4; *(ushort4*)(m1h+fo+4)=z4;
        *(ushort4*)(m1l+fo)=z4; *(ushort4*)(m1l+fo+4)=z4;
        return;
    }

    size_t ge = (size_t)(g0 + 2*pb)*DEG_ + r;
    int b = (int)(ge / E_);
    int ii = eidx[2*ge], jj = eidx[2*ge+1];
    int ni = b*N_+ii, nj = b*N_+jj;
    float em = emask[ge];
    float dx=(x[ni*3+0]-x[nj*3+0])*em;
    float dy=(x[ni*3+1]-x[nj*3+1])*em;
    float dz=(x[ni*3+2]-x[nj*3+2])*em;
    float d2 = dx*dx+dy*dy+dz*dz;
    float av = a[ge];
    size_t nio = (size_t)ni*H_ + kb;
    size_t njo = (size_t)nj*H_ + kb;

    // --- u1 (x-path) ---
    {
        float4 i0 = *(const float4*)(XHi+nio),   i1 = *(const float4*)(XHi+nio+4);
        float4 j0 = *(const float4*)(XHj+njo),   j1 = *(const float4*)(XHj+njo+4);
        float4 w50= *(const float4*)(xw512+kb),  w51= *(const float4*)(xw512+kb+4);
        float4 w60= *(const float4*)(xw513+kb),  w61= *(const float4*)(xw513+kb+4);
        float4 b0 = *(const float4*)(xb1+kb),    b1v= *(const float4*)(xb1+kb+4);
        float v[8];
        v[0]=siluf_(i0.x+j0.x+d2*w50.x+av*w60.x+b0.x);
        v[1]=siluf_(i0.y+j0.y+d2*w50.y+av*w60.y+b0.y);
        v[2]=siluf_(i0.z+j0.z+d2*w50.z+av*w60.z+b0.z);
        v[3]=siluf_(i0.w+j0.w+d2*w50.w+av*w60.w+b0.w);
        v[4]=siluf_(i1.x+j1.x+d2*w51.x+av*w61.x+b1v.x);
        v[5]=siluf_(i1.y+j1.y+d2*w51.y+av*w61.y+b1v.y);
        v[6]=siluf_(i1.z+j1.z+d2*w51.z+av*w61.z+b1v.z);
        v[7]=siluf_(i1.w+j1.w+d2*w51.w+av*w61.w+b1v.w);
        ushort hh[8], ll[8];
        #pragma unroll
        for (int q=0;q<8;q++){ hh[q]=f2bf(v[q]); ll[q]=f2bf(v[q]-bf2f(hh[q])); }
        *(ushort4*)(u1h+fo)   = make_ushort4(hh[0],hh[1],hh[2],hh[3]);
        *(ushort4*)(u1h+fo+4) = make_ushort4(hh[4],hh[5],hh[6],hh[7]);
        *(ushort4*)(u1l+fo)   = make_ushort4(ll[0],ll[1],ll[2],ll[3]);
        *(ushort4*)(u1l+fo+4) = make_ushort4(ll[4],ll[5],ll[6],ll[7]);
    }
    // --- m1 (h-path) ---
    {
        float4 i0 = *(const float4*)(EHi+nio),   i1 = *(const float4*)(EHi+nio+4);
        float4 j0 = *(const float4*)(EHj+njo),   j1 = *(const float4*)(EHj+njo+4);
        float4 w50= *(const float4*)(ew512+kb),  w51= *(const float4*)(ew512+kb+4);
        float4 w60= *(const float4*)(ew513+kb),  w61= *(const float4*)(ew513+kb+4);
        float4 b0 = *(const float4*)(eb1+kb),    b1v= *(const float4*)(eb1+kb+4);
        float v[8];
        v[0]=siluf_(i0.x+j0.x+d2*w50.x+av*w60.x+b0.x);
        v[1]=siluf_(i0.y+j0.y+d2*w50.y+av*w60.y+b0.y);
        v[2]=siluf_(i0.z+j0.z+d2*w50.z+av*w60.z+b0.z);
        v[3]=siluf_(i0.w+j0.w+d2*w50.w+av*w60.w+b0.w);
        v[4]=siluf_(i1.x+j1.x+d2*w51.x+av*w61.x+b1v.x);
        v[5]=siluf_(i1.y+j1.y+d2*w51.y+av*w61.y+b1v.y);
        v[6]=siluf_(i1.z+j1.z+d2*w51.z+av*w61.z+b1v.z);
        v[7]=siluf_(i1.w+j1.w+d2*w51.w+av*w61.w+b1v.w);
        ushort hh[8], ll[8];
        #pragma unroll
        for (int q=0;q<8;q++){ hh[q]=f2bf(v[q]); ll[q]=f2bf(v[q]-bf2f(hh[q])); }
        *(ushort4*)(m1h+fo)   = make_ushort4(hh[0],hh[1],hh[2],hh[3]);
        *(ushort4*)(m1h+fo+4) = make_ushort4(hh[4],hh[5],hh[6],hh[7]);
        *(ushort4*)(m1l+fo)   = make_ushort4(ll[0],ll[1],ll[2],ll[3]);
        *(ushort4*)(m1l+fo+4) = make_ushort4(ll[4],ll[5],ll[6],ll[7]);
    }
}

// ---------------- shared MFMA mainloop over one 64-row band (bf16x3) ----------------
__device__ __forceinline__ void mfma_band(
    const ushort* __restrict__ apH, const ushort* __restrict__ apL,
    const ushort* __restrict__ bp, f32x4 (&acc)[4][4])
{
    #pragma unroll
    for (int ks=0; ks<8; ++ks){
        bf16x8 ah[4], al[4];
        #pragma unroll
        for (int rt=0; rt<4; ++rt){
            ah[rt] = *(const bf16x8*)(apH + (ks*4+rt)*512);
            al[rt] = *(const bf16x8*)(apL + (ks*4+rt)*512);
        }
        #pragma unroll
        for (int ct=0; ct<4; ++ct){
            bf16x8 bh = *(const bf16x8*)(bp + ks*8192 + ct*512);
            bf16x8 bl = *(const bf16x8*)(bp + 65536 + ks*8192 + ct*512);
            #pragma unroll
            for (int rt=0; rt<4; ++rt){
                acc[rt][ct] = __builtin_amdgcn_mfma_f32_16x16x32_bf16(ah[rt], bh, acc[rt][ct], 0,0,0);
                acc[rt][ct] = __builtin_amdgcn_mfma_f32_16x16x32_bf16(al[rt], bh, acc[rt][ct], 0,0,0);
                acc[rt][ct] = __builtin_amdgcn_mfma_f32_16x16x32_bf16(ah[rt], bl, acc[rt][ct], 0,0,0);
            }
        }
    }
}

// ---------------- fused edge GEMM (U + M passes) + scatter epilogue ----------------
// Block = node pair (56 real edges padded to 64 rows) x 256 cols; 4 waves = col quarters.
// U pass -> pdU (LDS); M pass -> pdM (LDS) + v kept in regs.
// Wave 0: per-edge tanh/sigmoid, x_new update (exclusive). All waves: agg from regs (exclusive).
__global__ __launch_bounds__(256, 4)
void k_edge_fused(const ushort* __restrict__ u1h, const ushort* __restrict__ u1l,
                  const ushort* __restrict__ m1h, const ushort* __restrict__ m1l,
                  const ushort* __restrict__ WfU, const ushort* __restrict__ WfM,
                  const float* __restrict__ xb2, const float* __restrict__ xw3,
                  const float* __restrict__ eb2, const float* __restrict__ attw,
                  const float* __restrict__ attb,
                  const float* __restrict__ x_cur, float* __restrict__ x_new,
                  const int* __restrict__ eidx, const float* __restrict__ emask,
                  const float* __restrict__ nmask,
                  float* __restrict__ agg, int g0)
{
    const int tid  = threadIdx.x;
    const int lane = tid & 63;
    const int ch   = tid >> 6;    // col quarter (0..3)
    const int g    = lane >> 4;
    const int li   = lane & 15;
    const int pb   = blockIdx.x;
    const int n0   = g0 + 2*pb;                 // first node of pair (global row in agg/x)
    const size_t geb = (size_t)n0*DEG_;         // first global edge

    __shared__ float pdLds[2][4][64];
    __shared__ float easLds[64];
    __shared__ float cxyz[2*DEG_][3];

    const ushort* apHU = u1h + (size_t)pb*16384 + (size_t)lane*8;
    const ushort* apLU = u1l + (size_t)pb*16384 + (size_t)lane*8;
    const ushort* apHM = m1h + (size_t)pb*16384 + (size_t)lane*8;
    const ushort* apLM = m1l + (size_t)pb*16384 + (size_t)lane*8;
    const ushort* bpU  = WfU + ((size_t)(ch*4)*64 + lane)*8;
    const ushort* bpM  = WfM + ((size_t)(ch*4)*64 + lane)*8;

    f32x4 acc[4][4];

    // ================= U pass =================
    #pragma unroll
    for (int rt=0;rt<4;++rt)
        #pragma unroll
        for (int ct=0;ct<4;++ct)
            acc[rt][ct] = (f32x4){0.f,0.f,0.f,0.f};
    mfma_band(apHU, apLU, bpU, acc);
    {
        float pdv[4][4];
        #pragma unroll
        for (int rt=0;rt<4;++rt)
            #pragma unroll
            for (int rg=0;rg<4;++rg) pdv[rt][rg]=0.f;
        #pragma unroll
        for (int ct=0; ct<4; ++ct){
            const int col = ch*64 + ct*16 + li;
            const float bi = xb2[col];
            const float wv = xw3[col];
            #pragma unroll
            for (int rt=0; rt<4; ++rt)
                #pragma unroll
                for (int rg=0; rg<4; ++rg)
                    pdv[rt][rg] += siluf_(acc[rt][ct][rg] + bi)*wv;
        }
        #pragma unroll
        for (int rt=0;rt<4;++rt)
            #pragma unroll
            for (int rg=0;rg<4;++rg){
                float s = pdv[rt][rg];
                s += __shfl_xor(s, 1, 16);
                s += __shfl_xor(s, 2, 16);
                s += __shfl_xor(s, 4, 16);
                s += __shfl_xor(s, 8, 16);
                if (li==0) pdLds[0][ch][rt*16 + g*4 + rg] = s;
            }
    }

    // ================= M pass =================
    #pragma unroll
    for (int rt=0;rt<4;++rt)
        #pragma unroll
        for (int ct=0;ct<4;++ct)
            acc[rt][ct] = (f32x4){0.f,0.f,0.f,0.f};
    mfma_band(apHM, apLM, bpM, acc);
    {
        float pdv[4][4];
        #pragma unroll
        for (int rt=0;rt<4;++rt)
            #pragma unroll
            for (int rg=0;rg<4;++rg) pdv[rt][rg]=0.f;
        #pragma unroll
        for (int ct=0; ct<4; ++ct){
            const int col = ch*64 + ct*16 + li;
            const float bi = eb2[col];
            const float wv = attw[col];
            #pragma unroll
            for (int rt=0; rt<4; ++rt)
                #pragma unroll
                for (int rg=0; rg<4; ++rg){
                    float v = siluf_(acc[rt][ct][rg] + bi);
                    acc[rt][ct][rg] = v;          // keep silu'd M2 value for agg
                    pdv[rt][rg] += v*wv;
                }
        }
        #pragma unroll
        for (int rt=0;rt<4;++rt)
            #pragma unroll
            for (int rg=0;rg<4;++rg){
                float s = pdv[rt][rg];
                s += __shfl_xor(s, 1, 16);
                s += __shfl_xor(s, 2, 16);
                s += __shfl_xor(s, 4, 16);
                s += __shfl_xor(s, 8, 16);
                if (li==0) pdLds[1][ch][rt*16 + g*4 + rg] = s;
            }
    }

    __syncthreads();

    // ============ per-edge scalar phase (wave 0) ============
    if (ch == 0){
        int t = lane;
        float ea = 0.f;
        if (t < 2*DEG_){
            float sU = pdLds[0][0][t]+pdLds[0][1][t]+pdLds[0][2][t]+pdLds[0][3][t];
            float sM = pdLds[1][0][t]+pdLds[1][1][t]+pdLds[1][2][t]+pdLds[1][3][t];
            float tsc = tanhf(sU)*SCALE_;
            ea = sigmoidf_(sM + attb[0]);
            size_t ge = geb + t;
            int drow = n0 + (t >= DEG_ ? 1 : 0);
            int b = drow / N_;
            int jj = eidx[2*ge+1];
            int nj = b*N_ + jj;
            float em = emask[ge];
            float dx=(x_cur[drow*3+0]-x_cur[nj*3+0])*em;
            float dy=(x_cur[drow*3+1]-x_cur[nj*3+1])*em;
            float dz=(x_cur[drow*3+2]-x_cur[nj*3+2])*em;
            float dd = sqrtf(dx*dx+dy*dy+dz*dz);
            float sc = tsc/(dd+1.0f);
            cxyz[t][0]=sc*dx; cxyz[t][1]=sc*dy; cxyz[t][2]=sc*dz;
        }
        easLds[t] = (t < 2*DEG_) ? ea : 0.f;
        if (t == 0 || t == DEG_){
            int node = n0 + (t ? 1 : 0);
            float sx=0.f, sy=0.f, sz=0.f;
            #pragma unroll 4
            for (int k=0;k<DEG_;k++){ sx+=cxyz[t+k][0]; sy+=cxyz[t+k][1]; sz+=cxyz[t+k][2]; }
            float nm = nmask[node];
            x_new[node*3+0]=(x_cur[node*3+0]+sx)*nm;
            x_new[node*3+1]=(x_cur[node*3+1]+sy)*nm;
            x_new[node*3+2]=(x_cur[node*3+2]+sz)*nm;
        }
    }
    __syncthreads();

    // ============ agg from register-resident M2 ============
    float p0[4] = {0.f,0.f,0.f,0.f};
    float p1[4] = {0.f,0.f,0.f,0.f};
    #pragma unroll
    for (int rt=0; rt<4; ++rt){
        #pragma unroll
        for (int rg=0; rg<4; ++rg){
            int row = rt*16 + g*4 + rg;
            float w = easLds[row];
            bool hi = (row >= DEG_);
            #pragma unroll
            for (int ct=0; ct<4; ++ct){
                float x = w*acc[rt][ct][rg];
                p0[ct] += hi ? 0.f : x;
                p1[ct] += hi ? x : 0.f;
            }
        }
    }
    #pragma unroll
    for (int ct=0; ct<4; ++ct){
        p0[ct] += __shfl_xor(p0[ct], 16);
        p0[ct] += __shfl_xor(p0[ct], 32);
        p1[ct] += __shfl_xor(p1[ct], 16);
        p1[ct] += __shfl_xor(p1[ct], 32);
    }
    if (g == 0){
        #pragma unroll
        for (int ct=0; ct<4; ++ct){
            int col = ch*64 + ct*16 + li;
            agg[(size_t)n0*H_ + col]     = p0[ct];
            agg[(size_t)(n0+1)*H_ + col] = p1[ct];
        }
    }
}

// ---------------- outputs ----------------
__global__ void k_out_x(const float* __restrict__ x, const float* __restrict__ x_in,
                        const float* __restrict__ nmask, float* __restrict__ out)
{
    int b = blockIdx.x; int l = threadIdx.x;
    int row = b*N_ + l;
    float xd0=0.f,xd1=0.f,xd2=0.f,nm=0.f;
    if (l < N_) {
        nm = nmask[row];
        xd0 = (x[(size_t)row*3+0]-x_in[(size_t)row*3+0])*nm;
        xd1 = (x[(size_t)row*3+1]-x_in[(size_t)row*3+1])*nm;
        xd2 = (x[(size_t)row*3+2]-x_in[(size_t)row*3+2])*nm;
    }
    float s0=xd0,s1=xd1,s2=xd2,sn=nm;
    #pragma unroll
    for (int off=32; off; off>>=1) {
        s0+=__shfl_xor(s0,off,64); s1+=__shfl_xor(s1,off,64);
        s2+=__shfl_xor(s2,off,64); sn+=__shfl_xor(sn,off,64);
    }
    float m0=s0/sn, m1=s1/sn, m2=s2/sn;
    if (l < N_) {
        out[(size_t)row*8+0]=(xd0-m0)*nm;
        out[(size_t)row*8+1]=(xd1-m1)*nm;
        out[(size_t)row*8+2]=(xd2-m2)*nm;
    }
}

__global__ void k_out_h(const float* __restrict__ h, const float* __restrict__ wout_w, const float* __restrict__ wout_b,
                        const float* __restrict__ nmask, float* __restrict__ out)
{
    int row = blockIdx.x; int lane = threadIdx.x;
    int c4 = lane<<2;
    float4 hv = *(const float4*)(h + (size_t)row*H_ + c4);
    float p0=0,p1=0,p2=0,p3=0,p4=0;
    float hvv[4] = {hv.x,hv.y,hv.z,hv.w};
    #pragma unroll
    for (int j=0;j<4;j++) {
        int k = c4+j;
        float hval = hvv[j];
        p0 += hval * wout_w[k*6+0];
        p1 += hval * wout_w[k*6+1];
        p2 += hval * wout_w[k*6+2];
        p3 += hval * wout_w[k*6+3];
        p4 += hval * wout_w[k*6+4];
    }
    #pragma unroll
    for (int off=32; off; off>>=1) {
        p0+=__shfl_xor(p0,off,64); p1+=__shfl_xor(p1,off,64); p2+=__shfl_xor(p2,off,64);
        p3+=__shfl_xor(p3,off,64); p4+=__shfl_xor(p4,off,64);
    }
    if (lane==0) {
        float nm = nmask[row];
        out[(size_t)row*8+3] = (p0+wout_b[0])*nm;
        out[(size_t)row*8+4] = (p1+wout_b[1])*nm;
        out[(size_t)row*8+5] = (p2+wout_b[2])*nm;
        out[(size_t)row*8+6] = (p3+wout_b[3])*nm;
        out[(size_t)row*8+7] = (p4+wout_b[4])*nm;
    }
}

extern "C" void kernel_launch(void* const* d_in, const int* in_sizes, int n_in,
                              void* d_out, int out_size, void* d_ws, size_t ws_size,
                              hipStream_t stream)
{
    const float* x_in  = (const float*)d_in[0];
    const float* h_in  = (const float*)d_in[1];
    const float* t     = (const float*)d_in[2];
    const float* nmask = (const float*)d_in[3];
    const float* emask = (const float*)d_in[4];
    const int*   eidx  = (const int*)d_in[5];
    const float* win_w = (const float*)d_in[6];
    const float* win_b = (const float*)d_in[7];
    const float* wout_w= (const float*)d_in[8];
    const float* wout_b= (const float*)d_in[9];
    const float* e_w1  = (const float*)d_in[10];
    const float* e_b1  = (const float*)d_in[11];
    const float* e_w2  = (const float*)d_in[12];
    const float* e_b2  = (const float*)d_in[13];
    const float* att_w = (const float*)d_in[14];
    const float* att_b = (const float*)d_in[15];
    const float* h_w1  = (const float*)d_in[16];
    const float* h_b1  = (const float*)d_in[17];
    const float* h_w2  = (const float*)d_in[18];
    const float* h_b2  = (const float*)d_in[19];
    const float* x_w1  = (const float*)d_in[20];
    const float* x_b1  = (const float*)d_in[21];
    const float* x_w2  = (const float*)d_in[22];
    const float* x_b2  = (const float*)d_in[23];
    const float* x_w3  = (const float*)d_in[24];
    float* out = (float*)d_out;

    char* ws = (char*)d_ws;
    size_t off = 0;
    auto alloc = [&](size_t bytes)->float* {
        float* p = (float*)(ws + off);
        off = (off + bytes + 255) & ~(size_t)255;
        return p;
    };
    float* h    = alloc((size_t)BN_*H_*4);
    float* xA   = alloc((size_t)BN_*3*4);
    float* xB   = alloc((size_t)BN_*3*4);
    float* a    = alloc((size_t)BE_*4);
    float* NB5  = alloc((size_t)5*BN_*H_*4);
    float* agg  = alloc((size_t)BN_*H_*4);
    float* hm1  = alloc((size_t)BN_*H_*4);
    // fragmentized W (bf16 hi/lo), all layers, both passes: L * 131072 ushorts each
    ushort* WfU = (ushort*)alloc((size_t)L_*131072*sizeof(ushort));
    ushort* WfM = (ushort*)alloc((size_t)L_*131072*sizeof(ushort));

    // chunked edge fragment planes (u1/m1 hi+lo), banded by node PAIR: 131072 B per pair
    size_t avail = (ws_size > off + (2<<20)) ? (ws_size - off - (2<<20)) : 0;
    long pcap = (long)(avail / 131072);
    if (pcap < 1) pcap = 1;
    long gcap = 2*pcap;
    if (gcap > BN_) gcap = BN_;
    int nc  = (int)((BN_ + gcap - 1)/gcap);
    int gpc = (BN_ + nc - 1)/nc;
    gpc += (gpc & 1);                     // even nodes per chunk (whole pairs)
    if (gpc > BN_) gpc = BN_;
    nc = (BN_ + gpc - 1)/gpc;
    int pcapc = gpc/2;
    size_t planeElems = (size_t)pcapc*16384;    // ushorts per plane
    ushort* u1h = (ushort*)alloc(planeElems*2*sizeof(ushort));  // hi + lo
    ushort* u1l = u1h + planeElems;
    ushort* m1h = (ushort*)alloc(planeElems*2*sizeof(ushort));
    ushort* m1l = m1h + planeElems;

    k_init_h<<<BN_, H_, 0, stream>>>(h_in, t, win_w, win_b, h);
    k_init_xa<<<(BE_+255)/256, 256, 0, stream>>>(x_in, eidx, emask, xA, a);
    k_wprep<<<(L_*2*8192+255)/256, 256, 0, stream>>>(x_w2, e_w2, WfU, WfM);

    float* x_cur = xA;
    float* x_new = xB;

    for (int l=0; l<L_; l++) {
        const float* xw1l = x_w1 + (size_t)l*514*H_;
        const float* ew1l = e_w1 + (size_t)l*514*H_;
        const float* hw1l = h_w1 + (size_t)l*512*H_;

        // 5 node-side GEMMs sharing A=h: XHi, XHj, EHi, EHj, Htop
        GArgs na = {};
        const float* Bz[5] = { xw1l, xw1l+(size_t)256*H_, ew1l, ew1l+(size_t)256*H_, hw1l };
        for (int z=0;z<5;z++){
            na.g[z].A=h; na.g[z].Bw=Bz[z]; na.g[z].bias=nullptr; na.g[z].add=nullptr;
            na.g[z].rmask=nullptr; na.g[z].C=NB5 + (size_t)z*BN_*H_;
        }
        k_gemm64<0><<<dim3(BN_/64, H_/64, 5),256,0,stream>>>(na, BN_, H_);

        float* XHi=NB5;
        float* XHj=NB5+(size_t)BN_*H_;
        float* EHi=NB5+(size_t)2*BN_*H_;
        float* EHj=NB5+(size_t)3*BN_*H_;
        float* Htop=NB5+(size_t)4*BN_*H_;

        for (int c=0;c<nc;c++) {
            int g0 = c*gpc;
            int g1 = (g0+gpc < BN_) ? (g0+gpc) : BN_;
            int ng = g1-g0;
            if (ng <= 0) break;
            int npairs = ng/2;

            k_edge_mlp1<<<npairs*8,256,0,stream>>>(XHi,XHj,EHi,EHj, x_cur, a, eidx, emask,
                xw1l+(size_t)512*H_, xw1l+(size_t)513*H_, x_b1+(size_t)l*H_,
                ew1l+(size_t)512*H_, ew1l+(size_t)513*H_, e_b1+(size_t)l*H_,
                u1h, u1l, m1h, m1l, g0, npairs);

            k_edge_fused<<<npairs,256,0,stream>>>(u1h, u1l, m1h, m1l,
                WfU + (size_t)l*131072, WfM + (size_t)l*131072,
                x_b2+(size_t)l*H_, x_w3+(size_t)l*H_,
                e_b2+(size_t)l*H_, att_w+(size_t)l*H_, att_b+l,
                x_cur, x_new, eidx, emask, nmask, agg, g0);
        }

        GArgs ha = {};
        ha.g[0] = { agg, hw1l+(size_t)256*H_, h_b1+(size_t)l*H_, Htop, nullptr, hm1 };
        k_gemm64<1><<<dim3(BN_/64,H_/64,1),256,0,stream>>>(ha, BN_, H_);

        GArgs h2 = {};
        h2.g[0] = { hm1, h_w2+(size_t)l*H_*H_, h_b2+(size_t)l*H_, h, nmask, h };
        k_gemm64<0><<<dim3(BN_/64,H_/64,1),256,0,stream>>>(h2, BN_, H_);

        float* tmp = x_cur; x_cur = x_new; x_new = tmp;
    }

    k_out_x<<<B_,64,0,stream>>>(x_cur, x_in, nmask, out);
    k_out_h<<<BN_,64,0,stream>>>(h, wout_w, wout_b, nmask, out);
}

// Round 7
// 1471.673 us; speedup vs baseline: 1.0715x; 1.0715x over previous
//
#include <hip/hip_runtime.h>
#include <math.h>

#define B_ 64
#define N_ 29
#define E_ 812
#define L_ 9
#define H_ 256
#define FA_ 5
#define BN_ (B_*N_)   // 1856
#define BE_ (B_*E_)   // 51968
#define DEG_ 28
#define SCALE_ 15.0f

typedef __attribute__((ext_vector_type(8))) short bf16x8;
typedef __attribute__((ext_vector_type(4))) float f32x4;

__device__ __forceinline__ float sigmoidf_(float v){ return 1.0f/(1.0f+expf(-v)); }
__device__ __forceinline__ float siluf_(float v){ return v/(1.0f+expf(-v)); }

// bf16 round-to-nearest-even conversion + back
__device__ __forceinline__ ushort f2bf(float f){
    uint u = __float_as_uint(f);
    u += 0x7fffu + ((u>>16)&1u);
    return (ushort)(u>>16);
}
__device__ __forceinline__ float bf2f(ushort h){ return __uint_as_float(((uint)h)<<16); }

// ---------------- init ----------------
__global__ void k_init_h(const float* __restrict__ h_in, const float* __restrict__ t,
                         const float* __restrict__ win_w, const float* __restrict__ win_b,
                         float* __restrict__ h)
{
    int node = blockIdx.x; int c = threadIdx.x;
    float in[6];
    #pragma unroll
    for (int k=0;k<FA_;k++) in[k] = h_in[node*FA_+k];
    in[5] = t[node];
    float acc = win_b[c];
    #pragma unroll
    for (int k=0;k<6;k++) acc += in[k]*win_w[k*H_+c];
    h[(size_t)node*H_+c] = acc;
}

__global__ void k_init_xa(const float* __restrict__ x_in, const int* __restrict__ eidx,
                          const float* __restrict__ emask, float* __restrict__ x, float* __restrict__ a)
{
    int gid = blockIdx.x*256 + threadIdx.x;
    if (gid < BN_*3) x[gid] = x_in[gid];
    if (gid < BE_) {
        int b = gid / E_;
        int ii = eidx[2*gid], jj = eidx[2*gid+1];
        const float* xi = x_in + (size_t)(b*N_+ii)*3;
        const float* xj = x_in + (size_t)(b*N_+jj)*3;
        float dx = xi[0]-xj[0], dy = xi[1]-xj[1], dz = xi[2]-xj[2];
        a[gid] = sqrtf(dx*dx+dy*dy+dz*dz) * emask[gid];
    }
}

// ---------------- W fragmentization: row-major [K=256][N=256] fp32 -> MFMA B-frag bf16 hi/lo ----------------
// Layout per (layer,pass): hi plane [ks(8)][ct(16)][lane(64)][8] (65536 bf16), lo plane at +65536.
// Fragment semantic: lane holds B[k = ks*32 + (lane>>4)*8 + j][col = ct*16 + (lane&15)], j=0..7.
__global__ void k_wprep(const float* __restrict__ xw2, const float* __restrict__ ew2,
                        ushort* __restrict__ WfU, ushort* __restrict__ WfM)
{
    int gid = blockIdx.x*256 + threadIdx.x;
    if (gid >= L_*2*8192) return;
    int lane = gid & 63;
    int rest = gid >> 6;
    int ct = rest & 15; rest >>= 4;
    int ks = rest & 7;  rest >>= 3;
    int p  = rest & 1;  int l = rest >> 1;
    const float* src = (p ? ew2 : xw2) + (size_t)l*H_*H_;
    ushort* dst = (p ? WfM : WfU) + (size_t)l*131072;
    int g = lane>>4, li = lane&15;
    int col = ct*16 + li;
    int kb  = ks*32 + g*8;
    size_t fo = ((size_t)(ks*16+ct)*64 + lane)*8;
    ushort* dh = dst + fo;
    ushort* dl = dst + 65536 + fo;
    #pragma unroll
    for (int j=0;j<8;j++){
        float v = src[(size_t)(kb+j)*H_ + col];
        ushort h = f2bf(v);
        dh[j] = h;
        dl[j] = f2bf(v - bf2f(h));
    }
}

// ---------------- generic tiled fp32 GEMM (node-side) ----------------
struct GArg { const float* A; const float* Bw; const float* bias; const float* add; const float* rmask; float* C; };
struct GArgs { GArg g[6]; };

template<int ACT>
__global__ __launch_bounds__(256)
void k_gemm64(GArgs args, int M, int Kdim)
{
    const GArg ga = args.g[blockIdx.z];
    __shared__ float As[16*68];
    __shared__ float Bs[16*68];
    const int tid = threadIdx.x;
    const int row0 = blockIdx.x*64;
    const int col0 = blockIdx.y*64;
    const int ty = tid>>4, tx = tid&15;
    const int am = tid>>2, ak = (tid&3)<<2;
    const int bk = tid>>4, bn = (tid&15)<<2;
    float acc[4][4] = {};
    const float* Ap = ga.A + (size_t)min(row0+am, M-1)*Kdim + ak;
    const float* Bp = ga.Bw + (size_t)bk*H_ + col0 + bn;
    for (int k0=0; k0<Kdim; k0+=16) {
        float4 av = *(const float4*)(Ap + k0);
        float4 bv = *(const float4*)(Bp + (size_t)k0*H_);
        __syncthreads();
        As[(ak+0)*68+am]=av.x; As[(ak+1)*68+am]=av.y; As[(ak+2)*68+am]=av.z; As[(ak+3)*68+am]=av.w;
        *(float4*)&Bs[bk*68+bn] = bv;
        __syncthreads();
        #pragma unroll
        for (int k=0;k<16;k++) {
            float4 a4 = *(const float4*)&As[k*68 + (ty<<2)];
            float4 b4 = *(const float4*)&Bs[k*68 + (tx<<2)];
            float aa[4]={a4.x,a4.y,a4.z,a4.w};
            float bb[4]={b4.x,b4.y,b4.z,b4.w};
            #pragma unroll
            for (int i=0;i<4;i++)
                #pragma unroll
                for (int j=0;j<4;j++)
                    acc[i][j] = fmaf(aa[i], bb[j], acc[i][j]);
        }
    }
    const int r0 = row0 + (ty<<2);
    const int c0 = col0 + (tx<<2);
    float4 bias4 = make_float4(0.f,0.f,0.f,0.f);
    if (ga.bias) bias4 = *(const float4*)(ga.bias + c0);
    #pragma unroll
    for (int i=0;i<4;i++) {
        int r = r0+i;
        if (r >= M) break;
        float v0=acc[i][0]+bias4.x, v1=acc[i][1]+bias4.y, v2=acc[i][2]+bias4.z, v3=acc[i][3]+bias4.w;
        if (ga.add) {
            float4 ad = *(const float4*)(ga.add + (size_t)r*H_ + c0);
            v0+=ad.x; v1+=ad.y; v2+=ad.z; v3+=ad.w;
        }
        if (ACT==1) { v0=siluf_(v0); v1=siluf_(v1); v2=siluf_(v2); v3=siluf_(v3); }
        if (ga.rmask) { float mv = ga.rmask[r]; v0*=mv; v1*=mv; v2*=mv; v3*=mv; }
        *(float4*)(ga.C + (size_t)r*H_ + c0) = make_float4(v0,v1,v2,v3);
    }
}

// ---------------- in-LDS fragment compute (one 64-row band, one pass) ----------------
// fragH/fragL layout: [ks(8)][rt(4)][lane(64)][8] ushorts (32 KB each).
// Thread (wv,lane) fills rows rt=wv for all ks: row = wv*16 + (lane&15), k-octet = ks*32 + (lane>>4)*8.
__device__ __forceinline__ void frag_compute(
    const float* __restrict__ Xi, const float* __restrict__ Xj,
    const float* __restrict__ w5p, const float* __restrict__ w6p, const float* __restrict__ bp,
    int ni, int nj, float d2, float av, bool valid,
    int wv, int lane, int g,
    ushort (*fragH)[4][64][8], ushort (*fragL)[4][64][8])
{
    if (valid){
        const float* xi = Xi + (size_t)ni*H_;
        const float* xj = Xj + (size_t)nj*H_;
        #pragma unroll
        for (int ks=0; ks<8; ++ks){
            int kb = ks*32 + g*8;
            float4 i0 = *(const float4*)(xi + kb),  i1 = *(const float4*)(xi + kb + 4);
            float4 j0 = *(const float4*)(xj + kb),  j1 = *(const float4*)(xj + kb + 4);
            float4 w50= *(const float4*)(w5p + kb), w51= *(const float4*)(w5p + kb + 4);
            float4 w60= *(const float4*)(w6p + kb), w61= *(const float4*)(w6p + kb + 4);
            float4 b0 = *(const float4*)(bp + kb),  b1v= *(const float4*)(bp + kb + 4);
            float v[8];
            v[0]=siluf_(i0.x+j0.x+d2*w50.x+av*w60.x+b0.x);
            v[1]=siluf_(i0.y+j0.y+d2*w50.y+av*w60.y+b0.y);
            v[2]=siluf_(i0.z+j0.z+d2*w50.z+av*w60.z+b0.z);
            v[3]=siluf_(i0.w+j0.w+d2*w50.w+av*w60.w+b0.w);
            v[4]=siluf_(i1.x+j1.x+d2*w51.x+av*w61.x+b1v.x);
            v[5]=siluf_(i1.y+j1.y+d2*w51.y+av*w61.y+b1v.y);
            v[6]=siluf_(i1.z+j1.z+d2*w51.z+av*w61.z+b1v.z);
            v[7]=siluf_(i1.w+j1.w+d2*w51.w+av*w61.w+b1v.w);
            ushort hh[8], ll[8];
            #pragma unroll
            for (int q=0;q<8;q++){ hh[q]=f2bf(v[q]); ll[q]=f2bf(v[q]-bf2f(hh[q])); }
            *(ushort4*)&fragH[ks][wv][lane][0] = make_ushort4(hh[0],hh[1],hh[2],hh[3]);
            *(ushort4*)&fragH[ks][wv][lane][4] = make_ushort4(hh[4],hh[5],hh[6],hh[7]);
            *(ushort4*)&fragL[ks][wv][lane][0] = make_ushort4(ll[0],ll[1],ll[2],ll[3]);
            *(ushort4*)&fragL[ks][wv][lane][4] = make_ushort4(ll[4],ll[5],ll[6],ll[7]);
        }
    } else {
        ushort4 z4 = make_ushort4(0,0,0,0);
        #pragma unroll
        for (int ks=0; ks<8; ++ks){
            *(ushort4*)&fragH[ks][wv][lane][0] = z4;
            *(ushort4*)&fragH[ks][wv][lane][4] = z4;
            *(ushort4*)&fragL[ks][wv][lane][0] = z4;
            *(ushort4*)&fragL[ks][wv][lane][4] = z4;
        }
    }
}

// ---------------- MFMA mainloop reading A-fragments from LDS (bf16x3) ----------------
__device__ __forceinline__ void mfma_lds(
    const ushort (*fragH)[4][64][8], const ushort (*fragL)[4][64][8],
    const ushort* __restrict__ bp, int lane, f32x4 (&acc)[4][4])
{
    #pragma unroll
    for (int ks=0; ks<8; ++ks){
        bf16x8 ah[4], al[4];
        #pragma unroll
        for (int rt=0; rt<4; ++rt){
            ah[rt] = *(const bf16x8*)&fragH[ks][rt][lane][0];
            al[rt] = *(const bf16x8*)&fragL[ks][rt][lane][0];
        }
        #pragma unroll
        for (int ct=0; ct<4; ++ct){
            bf16x8 bh = *(const bf16x8*)(bp + ks*8192 + ct*512);
            bf16x8 bl = *(const bf16x8*)(bp + 65536 + ks*8192 + ct*512);
            #pragma unroll
            for (int rt=0; rt<4; ++rt){
                acc[rt][ct] = __builtin_amdgcn_mfma_f32_16x16x32_bf16(ah[rt], bh, acc[rt][ct], 0,0,0);
                acc[rt][ct] = __builtin_amdgcn_mfma_f32_16x16x32_bf16(al[rt], bh, acc[rt][ct], 0,0,0);
                acc[rt][ct] = __builtin_amdgcn_mfma_f32_16x16x32_bf16(ah[rt], bl, acc[rt][ct], 0,0,0);
            }
        }
    }
}

// ---------------- mega-fused edge kernel: frag compute + dual GEMM + scatter, all in one block ----------------
// Block = node pair (56 real edges padded to 64 rows) x 256 cols; 4 waves.
// Phases: u1 frags->LDS | U-GEMM (pdU) | m1 frags->LDS (overwrite) | M-GEMM (pdM, M2 in regs)
//         | per-edge scalars + x update (wave 0) | agg from regs.
__global__ __launch_bounds__(256, 2)
void k_edge_mega(const float* __restrict__ XHi, const float* __restrict__ XHj,
                 const float* __restrict__ EHi, const float* __restrict__ EHj,
                 const float* __restrict__ x_cur, const float* __restrict__ a,
                 const int* __restrict__ eidx, const float* __restrict__ emask,
                 const float* __restrict__ nmask,
                 const float* __restrict__ xw512, const float* __restrict__ xw513, const float* __restrict__ xb1,
                 const float* __restrict__ ew512, const float* __restrict__ ew513, const float* __restrict__ eb1,
                 const ushort* __restrict__ WfU, const ushort* __restrict__ WfM,
                 const float* __restrict__ xb2, const float* __restrict__ xw3,
                 const float* __restrict__ eb2, const float* __restrict__ attw,
                 const float* __restrict__ attb,
                 float* __restrict__ x_new, float* __restrict__ agg)
{
    __shared__ __align__(16) ushort fragH[8][4][64][8];   // 32 KB
    __shared__ __align__(16) ushort fragL[8][4][64][8];   // 32 KB
    __shared__ float pdLds[2][4][64];                     // 2 KB
    __shared__ float easLds[64];
    __shared__ float cxyz[2*DEG_][3];

    const int tid  = threadIdx.x;
    const int lane = tid & 63;
    const int wv   = tid >> 6;    // frag phase: row tile rt; GEMM phase: col quarter ch
    const int g    = lane >> 4;
    const int li   = lane & 15;
    const int pb   = blockIdx.x;
    const int n0   = 2*pb;

    // per-thread edge scalars for frag phases (row fixed per thread)
    const int frow = wv*16 + li;
    const bool valid = (frow < 2*DEG_);
    int ni=0, nj=0; float d2=0.f, av=0.f;
    if (valid){
        int drow = n0 + (frow >= DEG_ ? 1 : 0);
        int bb = drow / N_;
        size_t ge = (size_t)n0*DEG_ + frow;
        int jj = eidx[2*ge+1];
        ni = drow; nj = bb*N_ + jj;
        float em = emask[ge];
        float dx=(x_cur[ni*3+0]-x_cur[nj*3+0])*em;
        float dy=(x_cur[ni*3+1]-x_cur[nj*3+1])*em;
        float dz=(x_cur[ni*3+2]-x_cur[nj*3+2])*em;
        d2 = dx*dx+dy*dy+dz*dz;
        av = a[ge];
    }

    const ushort* bpU = WfU + ((size_t)(wv*4)*64 + lane)*8;
    const ushort* bpM = WfM + ((size_t)(wv*4)*64 + lane)*8;

    f32x4 acc[4][4];

    // ===== phase 1: u1 fragments -> LDS =====
    frag_compute(XHi, XHj, xw512, xw513, xb1, ni, nj, d2, av, valid, wv, lane, g, fragH, fragL);
    __syncthreads();

    // ===== phase 2: U-pass GEMM + pd epilogue =====
    #pragma unroll
    for (int rt=0;rt<4;++rt)
        #pragma unroll
        for (int ct=0;ct<4;++ct)
            acc[rt][ct] = (f32x4){0.f,0.f,0.f,0.f};
    mfma_lds(fragH, fragL, bpU, lane, acc);
    {
        float pdv[4][4];
        #pragma unroll
        for (int rt=0;rt<4;++rt)
            #pragma unroll
            for (int rg=0;rg<4;++rg) pdv[rt][rg]=0.f;
        #pragma unroll
        for (int ct=0; ct<4; ++ct){
            const int col = wv*64 + ct*16 + li;
            const float bi = xb2[col];
            const float wvv = xw3[col];
            #pragma unroll
            for (int rt=0; rt<4; ++rt)
                #pragma unroll
                for (int rg=0; rg<4; ++rg)
                    pdv[rt][rg] += siluf_(acc[rt][ct][rg] + bi)*wvv;
        }
        #pragma unroll
        for (int rt=0;rt<4;++rt)
            #pragma unroll
            for (int rg=0;rg<4;++rg){
                float s = pdv[rt][rg];
                s += __shfl_xor(s, 1, 16);
                s += __shfl_xor(s, 2, 16);
                s += __shfl_xor(s, 4, 16);
                s += __shfl_xor(s, 8, 16);
                if (li==0) pdLds[0][wv][rt*16 + g*4 + rg] = s;
            }
    }
    __syncthreads();

    // ===== phase 3: m1 fragments -> LDS (overwrite) =====
    frag_compute(EHi, EHj, ew512, ew513, eb1, ni, nj, d2, av, valid, wv, lane, g, fragH, fragL);
    __syncthreads();

    // ===== phase 4: M-pass GEMM + pd epilogue (M2 stays in regs) =====
    #pragma unroll
    for (int rt=0;rt<4;++rt)
        #pragma unroll
        for (int ct=0;ct<4;++ct)
            acc[rt][ct] = (f32x4){0.f,0.f,0.f,0.f};
    mfma_lds(fragH, fragL, bpM, lane, acc);
    {
        float pdv[4][4];
        #pragma unroll
        for (int rt=0;rt<4;++rt)
            #pragma unroll
            for (int rg=0;rg<4;++rg) pdv[rt][rg]=0.f;
        #pragma unroll
        for (int ct=0; ct<4; ++ct){
            const int col = wv*64 + ct*16 + li;
            const float bi = eb2[col];
            const float wvv = attw[col];
            #pragma unroll
            for (int rt=0; rt<4; ++rt)
                #pragma unroll
                for (int rg=0; rg<4; ++rg){
                    float v = siluf_(acc[rt][ct][rg] + bi);
                    acc[rt][ct][rg] = v;          // keep silu'd M2 value for agg
                    pdv[rt][rg] += v*wvv;
                }
        }
        #pragma unroll
        for (int rt=0;rt<4;++rt)
            #pragma unroll
            for (int rg=0;rg<4;++rg){
                float s = pdv[rt][rg];
                s += __shfl_xor(s, 1, 16);
                s += __shfl_xor(s, 2, 16);
                s += __shfl_xor(s, 4, 16);
                s += __shfl_xor(s, 8, 16);
                if (li==0) pdLds[1][wv][rt*16 + g*4 + rg] = s;
            }
    }
    __syncthreads();

    // ===== phase 5: per-edge scalars + x update (wave 0) =====
    if (wv == 0){
        int t = lane;
        float ea = 0.f;
        if (t < 2*DEG_){
            float sU = pdLds[0][0][t]+pdLds[0][1][t]+pdLds[0][2][t]+pdLds[0][3][t];
            float sM = pdLds[1][0][t]+pdLds[1][1][t]+pdLds[1][2][t]+pdLds[1][3][t];
            float tsc = tanhf(sU)*SCALE_;
            ea = sigmoidf_(sM + attb[0]);
            size_t ge = (size_t)n0*DEG_ + t;
            int drow = n0 + (t >= DEG_ ? 1 : 0);
            int bb = drow / N_;
            int jj = eidx[2*ge+1];
            int njs = bb*N_ + jj;
            float em = emask[ge];
            float dx=(x_cur[drow*3+0]-x_cur[njs*3+0])*em;
            float dy=(x_cur[drow*3+1]-x_cur[njs*3+1])*em;
            float dz=(x_cur[drow*3+2]-x_cur[njs*3+2])*em;
            float dd = sqrtf(dx*dx+dy*dy+dz*dz);
            float sc = tsc/(dd+1.0f);
            cxyz[t][0]=sc*dx; cxyz[t][1]=sc*dy; cxyz[t][2]=sc*dz;
        }
        easLds[t] = (t < 2*DEG_) ? ea : 0.f;
        if (t == 0 || t == DEG_){
            int node = n0 + (t ? 1 : 0);
            float sx=0.f, sy=0.f, sz=0.f;
            #pragma unroll 4
            for (int k=0;k<DEG_;k++){ sx+=cxyz[t+k][0]; sy+=cxyz[t+k][1]; sz+=cxyz[t+k][2]; }
            float nm = nmask[node];
            x_new[node*3+0]=(x_cur[node*3+0]+sx)*nm;
            x_new[node*3+1]=(x_cur[node*3+1]+sy)*nm;
            x_new[node*3+2]=(x_cur[node*3+2]+sz)*nm;
        }
    }
    __syncthreads();

    // ===== phase 6: agg from register-resident M2 =====
    float p0[4] = {0.f,0.f,0.f,0.f};
    float p1[4] = {0.f,0.f,0.f,0.f};
    #pragma unroll
    for (int rt=0; rt<4; ++rt){
        #pragma unroll
        for (int rg=0; rg<4; ++rg){
            int row = rt*16 + g*4 + rg;
            float w = easLds[row];
            bool hi = (row >= DEG_);
            #pragma unroll
            for (int ct=0; ct<4; ++ct){
                float xv = w*acc[rt][ct][rg];
                p0[ct] += hi ? 0.f : xv;
                p1[ct] += hi ? xv : 0.f;
            }
        }
    }
    #pragma unroll
    for (int ct=0; ct<4; ++ct){
        p0[ct] += __shfl_xor(p0[ct], 16);
        p0[ct] += __shfl_xor(p0[ct], 32);
        p1[ct] += __shfl_xor(p1[ct], 16);
        p1[ct] += __shfl_xor(p1[ct], 32);
    }
    if (g == 0){
        #pragma unroll
        for (int ct=0; ct<4; ++ct){
            int col = wv*64 + ct*16 + li;
            agg[(size_t)n0*H_ + col]     = p0[ct];
            agg[(size_t)(n0+1)*H_ + col] = p1[ct];
        }
    }
}

// ---------------- outputs ----------------
__global__ void k_out_x(const float* __restrict__ x, const float* __restrict__ x_in,
                        const float* __restrict__ nmask, float* __restrict__ out)
{
    int b = blockIdx.x; int l = threadIdx.x;
    int row = b*N_ + l;
    float xd0=0.f,xd1=0.f,xd2=0.f,nm=0.f;
    if (l < N_) {
        nm = nmask[row];
        xd0 = (x[(size_t)row*3+0]-x_in[(size_t)row*3+0])*nm;
        xd1 = (x[(size_t)row*3+1]-x_in[(size_t)row*3+1])*nm;
        xd2 = (x[(size_t)row*3+2]-x_in[(size_t)row*3+2])*nm;
    }
    float s0=xd0,s1=xd1,s2=xd2,sn=nm;
    #pragma unroll
    for (int off=32; off; off>>=1) {
        s0+=__shfl_xor(s0,off,64); s1+=__shfl_xor(s1,off,64);
        s2+=__shfl_xor(s2,off,64); sn+=__shfl_xor(sn,off,64);
    }
    float m0=s0/sn, m1=s1/sn, m2=s2/sn;
    if (l < N_) {
        out[(size_t)row*8+0]=(xd0-m0)*nm;
        out[(size_t)row*8+1]=(xd1-m1)*nm;
        out[(size_t)row*8+2]=(xd2-m2)*nm;
    }
}

__global__ void k_out_h(const float* __restrict__ h, const float* __restrict__ wout_w, const float* __restrict__ wout_b,
                        const float* __restrict__ nmask, float* __restrict__ out)
{
    int row = blockIdx.x; int lane = threadIdx.x;
    int c4 = lane<<2;
    float4 hv = *(const float4*)(h + (size_t)row*H_ + c4);
    float p0=0,p1=0,p2=0,p3=0,p4=0;
    float hvv[4] = {hv.x,hv.y,hv.z,hv.w};
    #pragma unroll
    for (int j=0;j<4;j++) {
        int k = c4+j;
        float hval = hvv[j];
        p0 += hval * wout_w[k*6+0];
        p1 += hval * wout_w[k*6+1];
        p2 += hval * wout_w[k*6+2];
        p3 += hval * wout_w[k*6+3];
        p4 += hval * wout_w[k*6+4];
    }
    #pragma unroll
    for (int off=32; off; off>>=1) {
        p0+=__shfl_xor(p0,off,64); p1+=__shfl_xor(p1,off,64); p2+=__shfl_xor(p2,off,64);
        p3+=__shfl_xor(p3,off,64); p4+=__shfl_xor(p4,off,64);
    }
    if (lane==0) {
        float nm = nmask[row];
        out[(size_t)row*8+3] = (p0+wout_b[0])*nm;
        out[(size_t)row*8+4] = (p1+wout_b[1])*nm;
        out[(size_t)row*8+5] = (p2+wout_b[2])*nm;
        out[(size_t)row*8+6] = (p3+wout_b[3])*nm;
        out[(size_t)row*8+7] = (p4+wout_b[4])*nm;
    }
}

extern "C" void kernel_launch(void* const* d_in, const int* in_sizes, int n_in,
                              void* d_out, int out_size, void* d_ws, size_t ws_size,
                              hipStream_t stream)
{
    const float* x_in  = (const float*)d_in[0];
    const float* h_in  = (const float*)d_in[1];
    const float* t     = (const float*)d_in[2];
    const float* nmask = (const float*)d_in[3];
    const float* emask = (const float*)d_in[4];
    const int*   eidx  = (const int*)d_in[5];
    const float* win_w = (const float*)d_in[6];
    const float* win_b = (const float*)d_in[7];
    const float* wout_w= (const float*)d_in[8];
    const float* wout_b= (const float*)d_in[9];
    const float* e_w1  = (const float*)d_in[10];
    const float* e_b1  = (const float*)d_in[11];
    const float* e_w2  = (const float*)d_in[12];
    const float* e_b2  = (const float*)d_in[13];
    const float* att_w = (const float*)d_in[14];
    const float* att_b = (const float*)d_in[15];
    const float* h_w1  = (const float*)d_in[16];
    const float* h_b1  = (const float*)d_in[17];
    const float* h_w2  = (const float*)d_in[18];
    const float* h_b2  = (const float*)d_in[19];
    const float* x_w1  = (const float*)d_in[20];
    const float* x_b1  = (const float*)d_in[21];
    const float* x_w2  = (const float*)d_in[22];
    const float* x_b2  = (const float*)d_in[23];
    const float* x_w3  = (const float*)d_in[24];
    float* out = (float*)d_out;

    char* ws = (char*)d_ws;
    size_t off = 0;
    auto alloc = [&](size_t bytes)->float* {
        float* p = (float*)(ws + off);
        off = (off + bytes + 255) & ~(size_t)255;
        return p;
    };
    float* h    = alloc((size_t)BN_*H_*4);
    float* xA   = alloc((size_t)BN_*3*4);
    float* xB   = alloc((size_t)BN_*3*4);
    float* a    = alloc((size_t)BE_*4);
    float* NB5  = alloc((size_t)5*BN_*H_*4);
    float* agg  = alloc((size_t)BN_*H_*4);
    float* hm1  = alloc((size_t)BN_*H_*4);
    // fragmentized W (bf16 hi/lo), all layers, both passes: L * 131072 ushorts each
    ushort* WfU = (ushort*)alloc((size_t)L_*131072*sizeof(ushort));
    ushort* WfM = (ushort*)alloc((size_t)L_*131072*sizeof(ushort));

    k_init_h<<<BN_, H_, 0, stream>>>(h_in, t, win_w, win_b, h);
    k_init_xa<<<(BE_+255)/256, 256, 0, stream>>>(x_in, eidx, emask, xA, a);
    k_wprep<<<(L_*2*8192+255)/256, 256, 0, stream>>>(x_w2, e_w2, WfU, WfM);

    float* x_cur = xA;
    float* x_new = xB;

    for (int l=0; l<L_; l++) {
        const float* xw1l = x_w1 + (size_t)l*514*H_;
        const float* ew1l = e_w1 + (size_t)l*514*H_;
        const float* hw1l = h_w1 + (size_t)l*512*H_;

        // 5 node-side GEMMs sharing A=h: XHi, XHj, EHi, EHj, Htop
        GArgs na = {};
        const float* Bz[5] = { xw1l, xw1l+(size_t)256*H_, ew1l, ew1l+(size_t)256*H_, hw1l };
        for (int z=0;z<5;z++){
            na.g[z].A=h; na.g[z].Bw=Bz[z]; na.g[z].bias=nullptr; na.g[z].add=nullptr;
            na.g[z].rmask=nullptr; na.g[z].C=NB5 + (size_t)z*BN_*H_;
        }
        k_gemm64<0><<<dim3(BN_/64, H_/64, 5),256,0,stream>>>(na, BN_, H_);

        float* XHi=NB5;
        float* XHj=NB5+(size_t)BN_*H_;
        float* EHi=NB5+(size_t)2*BN_*H_;
        float* EHj=NB5+(size_t)3*BN_*H_;
        float* Htop=NB5+(size_t)4*BN_*H_;

        // mega-fused edge pipeline: one block per node pair, no intermediates
        k_edge_mega<<<BN_/2, 256, 0, stream>>>(XHi, XHj, EHi, EHj, x_cur, a,
            eidx, emask, nmask,
            xw1l+(size_t)512*H_, xw1l+(size_t)513*H_, x_b1+(size_t)l*H_,
            ew1l+(size_t)512*H_, ew1l+(size_t)513*H_, e_b1+(size_t)l*H_,
            WfU + (size_t)l*131072, WfM + (size_t)l*131072,
            x_b2+(size_t)l*H_, x_w3+(size_t)l*H_,
            e_b2+(size_t)l*H_, att_w+(size_t)l*H_, att_b+l,
            x_new, agg);

        GArgs ha = {};
        ha.g[0] = { agg, hw1l+(size_t)256*H_, h_b1+(size_t)l*H_, Htop, nullptr, hm1 };
        k_gemm64<1><<<dim3(BN_/64,H_/64,1),256,0,stream>>>(ha, BN_, H_);

        GArgs h2 = {};
        h2.g[0] = { hm1, h_w2+(size_t)l*H_*H_, h_b2+(size_t)l*H_, h, nmask, h };
        k_gemm64<0><<<dim3(BN_/64,H_/64,1),256,0,stream>>>(h2, BN_, H_);

        float* tmp = x_cur; x_cur = x_new; x_new = tmp;
    }

    k_out_x<<<B_,64,0,stream>>>(x_cur, x_in, nmask, out);
    k_out_h<<<BN_,64,0,stream>>>(h, wout_w, wout_b, nmask, out);
}

// Round 9
// 1204.621 us; speedup vs baseline: 1.3091x; 1.2217x over previous
//
#include <hip/hip_runtime.h>
#include <math.h>

#define B_ 64
#define N_ 29
#define E_ 812
#define L_ 9
#define H_ 256
#define FA_ 5
#define BN_ (B_*N_)   // 1856
#define BE_ (B_*E_)   // 51968
#define DEG_ 28
#define SCALE_ 15.0f

typedef __attribute__((ext_vector_type(8))) short bf16x8;
typedef __attribute__((ext_vector_type(4))) float f32x4;

__device__ __forceinline__ float sigmoidf_(float v){ return 1.0f/(1.0f+expf(-v)); }
__device__ __forceinline__ float siluf_(float v){ return v/(1.0f+expf(-v)); }
// fast silu (edge path only): native exp + native rcp; ~5 ulp vs libm.
// Safe here: 6e-7 relative, 10x below the bf16x3 edge-GEMM error already proven invisible.
__device__ __forceinline__ float fsilu_(float v){
    float e = __expf(-v);
    return v * __builtin_amdgcn_rcpf(1.0f + e);
}

// bf16 round-to-nearest-even conversion + back (exact RNE, proven path)
__device__ __forceinline__ ushort f2bf(float f){
    uint u = __float_as_uint(f);
    u += 0x7fffu + ((u>>16)&1u);
    return (ushort)(u>>16);
}
__device__ __forceinline__ float bf2f(ushort h){ return __uint_as_float(((uint)h)<<16); }

// ---------------- init ----------------
__global__ void k_init_h(const float* __restrict__ h_in, const float* __restrict__ t,
                         const float* __restrict__ win_w, const float* __restrict__ win_b,
                         float* __restrict__ h)
{
    int node = blockIdx.x; int c = threadIdx.x;
    float in[6];
    #pragma unroll
    for (int k=0;k<FA_;k++) in[k] = h_in[node*FA_+k];
    in[5] = t[node];
    float acc = win_b[c];
    #pragma unroll
    for (int k=0;k<6;k++) acc += in[k]*win_w[k*H_+c];
    h[(size_t)node*H_+c] = acc;
}

__global__ void k_init_xa(const float* __restrict__ x_in, const int* __restrict__ eidx,
                          const float* __restrict__ emask, float* __restrict__ x, float* __restrict__ a)
{
    int gid = blockIdx.x*256 + threadIdx.x;
    if (gid < BN_*3) x[gid] = x_in[gid];
    if (gid < BE_) {
        int b = gid / E_;
        int ii = eidx[2*gid], jj = eidx[2*gid+1];
        const float* xi = x_in + (size_t)(b*N_+ii)*3;
        const float* xj = x_in + (size_t)(b*N_+jj)*3;
        float dx = xi[0]-xj[0], dy = xi[1]-xj[1], dz = xi[2]-xj[2];
        a[gid] = sqrtf(dx*dx+dy*dy+dz*dz) * emask[gid];
    }
}

// ---------------- W fragmentization: row-major [K=256][N=256] fp32 -> MFMA B-frag bf16 hi/lo ----------------
// Layout per (layer,pass): hi plane [ks(8)][ct(16)][lane(64)][8] (65536 bf16), lo plane at +65536.
// Fragment semantic: lane holds B[k = ks*32 + (lane>>4)*8 + j][col = ct*16 + (lane&15)], j=0..7.
__global__ void k_wprep(const float* __restrict__ xw2, const float* __restrict__ ew2,
                        ushort* __restrict__ WfU, ushort* __restrict__ WfM)
{
    int gid = blockIdx.x*256 + threadIdx.x;
    if (gid >= L_*2*8192) return;
    int lane = gid & 63;
    int rest = gid >> 6;
    int ct = rest & 15; rest >>= 4;
    int ks = rest & 7;  rest >>= 3;
    int p  = rest & 1;  int l = rest >> 1;
    const float* src = (p ? ew2 : xw2) + (size_t)l*H_*H_;
    ushort* dst = (p ? WfM : WfU) + (size_t)l*131072;
    int g = lane>>4, li = lane&15;
    int col = ct*16 + li;
    int kb  = ks*32 + g*8;
    size_t fo = ((size_t)(ks*16+ct)*64 + lane)*8;
    ushort* dh = dst + fo;
    ushort* dl = dst + 65536 + fo;
    #pragma unroll
    for (int j=0;j<8;j++){
        float v = src[(size_t)(kb+j)*H_ + col];
        ushort h = f2bf(v);
        dh[j] = h;
        dl[j] = f2bf(v - bf2f(h));
    }
}

// ---------------- generic tiled fp32 GEMM (node-side) ----------------
struct GArg { const float* A; const float* Bw; const float* bias; const float* add; const float* rmask; float* C; };
struct GArgs { GArg g[6]; };

template<int ACT>
__global__ __launch_bounds__(256)
void k_gemm64(GArgs args, int M, int Kdim)
{
    const GArg ga = args.g[blockIdx.z];
    __shared__ float As[16*68];
    __shared__ float Bs[16*68];
    const int tid = threadIdx.x;
    const int row0 = blockIdx.x*64;
    const int col0 = blockIdx.y*64;
    const int ty = tid>>4, tx = tid&15;
    const int am = tid>>2, ak = (tid&3)<<2;
    const int bk = tid>>4, bn = (tid&15)<<2;
    float acc[4][4] = {};
    const float* Ap = ga.A + (size_t)min(row0+am, M-1)*Kdim + ak;
    const float* Bp = ga.Bw + (size_t)bk*H_ + col0 + bn;
    for (int k0=0; k0<Kdim; k0+=16) {
        float4 av = *(const float4*)(Ap + k0);
        float4 bv = *(const float4*)(Bp + (size_t)k0*H_);
        __syncthreads();
        As[(ak+0)*68+am]=av.x; As[(ak+1)*68+am]=av.y; As[(ak+2)*68+am]=av.z; As[(ak+3)*68+am]=av.w;
        *(float4*)&Bs[bk*68+bn] = bv;
        __syncthreads();
        #pragma unroll
        for (int k=0;k<16;k++) {
            float4 a4 = *(const float4*)&As[k*68 + (ty<<2)];
            float4 b4 = *(const float4*)&Bs[k*68 + (tx<<2)];
            float aa[4]={a4.x,a4.y,a4.z,a4.w};
            float bb[4]={b4.x,b4.y,b4.z,b4.w};
            #pragma unroll
            for (int i=0;i<4;i++)
                #pragma unroll
                for (int j=0;j<4;j++)
                    acc[i][j] = fmaf(aa[i], bb[j], acc[i][j]);
        }
    }
    const int r0 = row0 + (ty<<2);
    const int c0 = col0 + (tx<<2);
    float4 bias4 = make_float4(0.f,0.f,0.f,0.f);
    if (ga.bias) bias4 = *(const float4*)(ga.bias + c0);
    #pragma unroll
    for (int i=0;i<4;i++) {
        int r = r0+i;
        if (r >= M) break;
        float v0=acc[i][0]+bias4.x, v1=acc[i][1]+bias4.y, v2=acc[i][2]+bias4.z, v3=acc[i][3]+bias4.w;
        if (ga.add) {
            float4 ad = *(const float4*)(ga.add + (size_t)r*H_ + c0);
            v0+=ad.x; v1+=ad.y; v2+=ad.z; v3+=ad.w;
        }
        if (ACT==1) { v0=siluf_(v0); v1=siluf_(v1); v2=siluf_(v2); v3=siluf_(v3); }
        if (ga.rmask) { float mv = ga.rmask[r]; v0*=mv; v1*=mv; v2*=mv; v3*=mv; }
        *(float4*)(ga.C + (size_t)r*H_ + c0) = make_float4(v0,v1,v2,v3);
    }
}

// ---------------- in-LDS fragment compute (one 64-row band, one pass) ----------------
// fragH/fragL layout: [ks(8)][rt(4)][lane(64)][8] ushorts (32 KB each).
// Thread (wv,lane) fills rows rt=wv for all ks: row = wv*16 + (lane&15), k-octet = ks*32 + (lane>>4)*8.
// Exact-RNE f2bf encode (proven); fast silu (edge path only).
__device__ __forceinline__ void frag_compute(
    const float* __restrict__ Xi, const float* __restrict__ Xj,
    const float* __restrict__ w5p, const float* __restrict__ w6p, const float* __restrict__ bp,
    int ni, int nj, float d2, float av, bool valid,
    int wv, int lane, int g,
    ushort (*fragH)[4][64][8], ushort (*fragL)[4][64][8])
{
    if (valid){
        const float* xi = Xi + (size_t)ni*H_;
        const float* xj = Xj + (size_t)nj*H_;
        #pragma unroll
        for (int ks=0; ks<8; ++ks){
            int kb = ks*32 + g*8;
            float4 i0 = *(const float4*)(xi + kb),  i1 = *(const float4*)(xi + kb + 4);
            float4 j0 = *(const float4*)(xj + kb),  j1 = *(const float4*)(xj + kb + 4);
            float4 w50= *(const float4*)(w5p + kb), w51= *(const float4*)(w5p + kb + 4);
            float4 w60= *(const float4*)(w6p + kb), w61= *(const float4*)(w6p + kb + 4);
            float4 b0 = *(const float4*)(bp + kb),  b1v= *(const float4*)(bp + kb + 4);
            float v[8];
            v[0]=fsilu_(i0.x+j0.x+d2*w50.x+av*w60.x+b0.x);
            v[1]=fsilu_(i0.y+j0.y+d2*w50.y+av*w60.y+b0.y);
            v[2]=fsilu_(i0.z+j0.z+d2*w50.z+av*w60.z+b0.z);
            v[3]=fsilu_(i0.w+j0.w+d2*w50.w+av*w60.w+b0.w);
            v[4]=fsilu_(i1.x+j1.x+d2*w51.x+av*w61.x+b1v.x);
            v[5]=fsilu_(i1.y+j1.y+d2*w51.y+av*w61.y+b1v.y);
            v[6]=fsilu_(i1.z+j1.z+d2*w51.z+av*w61.z+b1v.z);
            v[7]=fsilu_(i1.w+j1.w+d2*w51.w+av*w61.w+b1v.w);
            ushort hh[8], ll[8];
            #pragma unroll
            for (int q=0;q<8;q++){ hh[q]=f2bf(v[q]); ll[q]=f2bf(v[q]-bf2f(hh[q])); }
            *(ushort4*)&fragH[ks][wv][lane][0] = make_ushort4(hh[0],hh[1],hh[2],hh[3]);
            *(ushort4*)&fragH[ks][wv][lane][4] = make_ushort4(hh[4],hh[5],hh[6],hh[7]);
            *(ushort4*)&fragL[ks][wv][lane][0] = make_ushort4(ll[0],ll[1],ll[2],ll[3]);
            *(ushort4*)&fragL[ks][wv][lane][4] = make_ushort4(ll[4],ll[5],ll[6],ll[7]);
        }
    } else {
        ushort4 z4 = make_ushort4(0,0,0,0);
        #pragma unroll
        for (int ks=0; ks<8; ++ks){
            *(ushort4*)&fragH[ks][wv][lane][0] = z4;
            *(ushort4*)&fragH[ks][wv][lane][4] = z4;
            *(ushort4*)&fragL[ks][wv][lane][0] = z4;
            *(ushort4*)&fragL[ks][wv][lane][4] = z4;
        }
    }
}

// ---------------- MFMA mainloop reading A-fragments from LDS (bf16x3) ----------------
__device__ __forceinline__ void mfma_lds(
    const ushort (*fragH)[4][64][8], const ushort (*fragL)[4][64][8],
    const ushort* __restrict__ bp, int lane, f32x4 (&acc)[4][4])
{
    #pragma unroll
    for (int ks=0; ks<8; ++ks){
        bf16x8 ah[4], al[4];
        #pragma unroll
        for (int rt=0; rt<4; ++rt){
            ah[rt] = *(const bf16x8*)&fragH[ks][rt][lane][0];
            al[rt] = *(const bf16x8*)&fragL[ks][rt][lane][0];
        }
        #pragma unroll
        for (int ct=0; ct<4; ++ct){
            bf16x8 bh = *(const bf16x8*)(bp + ks*8192 + ct*512);
            bf16x8 bl = *(const bf16x8*)(bp + 65536 + ks*8192 + ct*512);
            #pragma unroll
            for (int rt=0; rt<4; ++rt){
                acc[rt][ct] = __builtin_amdgcn_mfma_f32_16x16x32_bf16(ah[rt], bh, acc[rt][ct], 0,0,0);
                acc[rt][ct] = __builtin_amdgcn_mfma_f32_16x16x32_bf16(al[rt], bh, acc[rt][ct], 0,0,0);
                acc[rt][ct] = __builtin_amdgcn_mfma_f32_16x16x32_bf16(ah[rt], bl, acc[rt][ct], 0,0,0);
            }
        }
    }
}

// ---------------- mega-fused edge kernel: frag compute + dual GEMM + scatter, all in one block ----------------
// Block = node pair (56 real edges padded to 64 rows) x 256 cols; 4 waves.
// Phases: u1 frags->LDS | U-GEMM (pdU) | m1 frags->LDS (overwrite) | M-GEMM (pdM, M2 in regs)
//         | per-edge scalars + x update (wave 0) | agg from regs.
__global__ __launch_bounds__(256, 2)
void k_edge_mega(const float* __restrict__ XHi, const float* __restrict__ XHj,
                 const float* __restrict__ EHi, const float* __restrict__ EHj,
                 const float* __restrict__ x_cur, const float* __restrict__ a,
                 const int* __restrict__ eidx, const float* __restrict__ emask,
                 const float* __restrict__ nmask,
                 const float* __restrict__ xw512, const float* __restrict__ xw513, const float* __restrict__ xb1,
                 const float* __restrict__ ew512, const float* __restrict__ ew513, const float* __restrict__ eb1,
                 const ushort* __restrict__ WfU, const ushort* __restrict__ WfM,
                 const float* __restrict__ xb2, const float* __restrict__ xw3,
                 const float* __restrict__ eb2, const float* __restrict__ attw,
                 const float* __restrict__ attb,
                 float* __restrict__ x_new, float* __restrict__ agg)
{
    __shared__ __align__(16) ushort fragH[8][4][64][8];   // 32 KB
    __shared__ __align__(16) ushort fragL[8][4][64][8];   // 32 KB
    __shared__ float pdLds[2][4][64];                     // 2 KB
    __shared__ float easLds[64];
    __shared__ float cxyz[2*DEG_][3];

    const int tid  = threadIdx.x;
    const int lane = tid & 63;
    const int wv   = tid >> 6;    // frag phase: row tile rt; GEMM phase: col quarter ch
    const int g    = lane >> 4;
    const int li   = lane & 15;
    const int pb   = blockIdx.x;
    const int n0   = 2*pb;

    // per-thread edge scalars for frag phases (row fixed per thread)
    const int frow = wv*16 + li;
    const bool valid = (frow < 2*DEG_);
    int ni=0, nj=0; float d2=0.f, av=0.f;
    if (valid){
        int drow = n0 + (frow >= DEG_ ? 1 : 0);
        int bb = drow / N_;
        size_t ge = (size_t)n0*DEG_ + frow;
        int jj = eidx[2*ge+1];
        ni = drow; nj = bb*N_ + jj;
        float em = emask[ge];
        float dx=(x_cur[ni*3+0]-x_cur[nj*3+0])*em;
        float dy=(x_cur[ni*3+1]-x_cur[nj*3+1])*em;
        float dz=(x_cur[ni*3+2]-x_cur[nj*3+2])*em;
        d2 = dx*dx+dy*dy+dz*dz;
        av = a[ge];
    }

    const ushort* bpU = WfU + ((size_t)(wv*4)*64 + lane)*8;
    const ushort* bpM = WfM + ((size_t)(wv*4)*64 + lane)*8;

    f32x4 acc[4][4];

    // ===== phase 1: u1 fragments -> LDS =====
    frag_compute(XHi, XHj, xw512, xw513, xb1, ni, nj, d2, av, valid, wv, lane, g, fragH, fragL);
    __syncthreads();

    // ===== phase 2: U-pass GEMM + pd epilogue =====
    #pragma unroll
    for (int rt=0;rt<4;++rt)
        #pragma unroll
        for (int ct=0;ct<4;++ct)
            acc[rt][ct] = (f32x4){0.f,0.f,0.f,0.f};
    mfma_lds(fragH, fragL, bpU, lane, acc);
    {
        float pdv[4][4];
        #pragma unroll
        for (int rt=0;rt<4;++rt)
            #pragma unroll
            for (int rg=0;rg<4;++rg) pdv[rt][rg]=0.f;
        #pragma unroll
        for (int ct=0; ct<4; ++ct){
            const int col = wv*64 + ct*16 + li;
            const float bi = xb2[col];
            const float wvv = xw3[col];
            #pragma unroll
            for (int rt=0; rt<4; ++rt)
                #pragma unroll
                for (int rg=0; rg<4; ++rg)
                    pdv[rt][rg] += fsilu_(acc[rt][ct][rg] + bi)*wvv;
        }
        #pragma unroll
        for (int rt=0;rt<4;++rt)
            #pragma unroll
            for (int rg=0;rg<4;++rg){
                float s = pdv[rt][rg];
                s += __shfl_xor(s, 1, 16);
                s += __shfl_xor(s, 2, 16);
                s += __shfl_xor(s, 4, 16);
                s += __shfl_xor(s, 8, 16);
                if (li==0) pdLds[0][wv][rt*16 + g*4 + rg] = s;
            }
    }
    __syncthreads();

    // ===== phase 3: m1 fragments -> LDS (overwrite) =====
    frag_compute(EHi, EHj, ew512, ew513, eb1, ni, nj, d2, av, valid, wv, lane, g, fragH, fragL);
    __syncthreads();

    // ===== phase 4: M-pass GEMM + pd epilogue (M2 stays in regs) =====
    #pragma unroll
    for (int rt=0;rt<4;++rt)
        #pragma unroll
        for (int ct=0;ct<4;++ct)
            acc[rt][ct] = (f32x4){0.f,0.f,0.f,0.f};
    mfma_lds(fragH, fragL, bpM, lane, acc);
    {
        float pdv[4][4];
        #pragma unroll
        for (int rt=0;rt<4;++rt)
            #pragma unroll
            for (int rg=0;rg<4;++rg) pdv[rt][rg]=0.f;
        #pragma unroll
        for (int ct=0; ct<4; ++ct){
            const int col = wv*64 + ct*16 + li;
            const float bi = eb2[col];
            const float wvv = attw[col];
            #pragma unroll
            for (int rt=0; rt<4; ++rt)
                #pragma unroll
                for (int rg=0; rg<4; ++rg){
                    float v = fsilu_(acc[rt][ct][rg] + bi);
                    acc[rt][ct][rg] = v;          // keep silu'd M2 value for agg
                    pdv[rt][rg] += v*wvv;
                }
        }
        #pragma unroll
        for (int rt=0;rt<4;++rt)
            #pragma unroll
            for (int rg=0;rg<4;++rg){
                float s = pdv[rt][rg];
                s += __shfl_xor(s, 1, 16);
                s += __shfl_xor(s, 2, 16);
                s += __shfl_xor(s, 4, 16);
                s += __shfl_xor(s, 8, 16);
                if (li==0) pdLds[1][wv][rt*16 + g*4 + rg] = s;
            }
    }
    __syncthreads();

    // ===== phase 5: per-edge scalars + x update (wave 0) =====
    if (wv == 0){
        int t = lane;
        float ea = 0.f;
        if (t < 2*DEG_){
            float sU = pdLds[0][0][t]+pdLds[0][1][t]+pdLds[0][2][t]+pdLds[0][3][t];
            float sM = pdLds[1][0][t]+pdLds[1][1][t]+pdLds[1][2][t]+pdLds[1][3][t];
            float tsc = tanhf(sU)*SCALE_;
            ea = sigmoidf_(sM + attb[0]);
            size_t ge = (size_t)n0*DEG_ + t;
            int drow = n0 + (t >= DEG_ ? 1 : 0);
            int bb = drow / N_;
            int jj = eidx[2*ge+1];
            int njs = bb*N_ + jj;
            float em = emask[ge];
            float dx=(x_cur[drow*3+0]-x_cur[njs*3+0])*em;
            float dy=(x_cur[drow*3+1]-x_cur[njs*3+1])*em;
            float dz=(x_cur[drow*3+2]-x_cur[njs*3+2])*em;
            float dd = sqrtf(dx*dx+dy*dy+dz*dz);
            float sc = tsc/(dd+1.0f);
            cxyz[t][0]=sc*dx; cxyz[t][1]=sc*dy; cxyz[t][2]=sc*dz;
        }
        easLds[t] = (t < 2*DEG_) ? ea : 0.f;
        if (t == 0 || t == DEG_){
            int node = n0 + (t ? 1 : 0);
            float sx=0.f, sy=0.f, sz=0.f;
            #pragma unroll 4
            for (int k=0;k<DEG_;k++){ sx+=cxyz[t+k][0]; sy+=cxyz[t+k][1]; sz+=cxyz[t+k][2]; }
            float nm = nmask[node];
            x_new[node*3+0]=(x_cur[node*3+0]+sx)*nm;
            x_new[node*3+1]=(x_cur[node*3+1]+sy)*nm;
            x_new[node*3+2]=(x_cur[node*3+2]+sz)*nm;
        }
    }
    __syncthreads();

    // ===== phase 6: agg from register-resident M2 =====
    float p0[4] = {0.f,0.f,0.f,0.f};
    float p1[4] = {0.f,0.f,0.f,0.f};
    #pragma unroll
    for (int rt=0; rt<4; ++rt){
        #pragma unroll
        for (int rg=0; rg<4; ++rg){
            int row = rt*16 + g*4 + rg;
            float w = easLds[row];
            bool hi = (row >= DEG_);
            #pragma unroll
            for (int ct=0; ct<4; ++ct){
                float xv = w*acc[rt][ct][rg];
                p0[ct] += hi ? 0.f : xv;
                p1[ct] += hi ? xv : 0.f;
            }
        }
    }
    #pragma unroll
    for (int ct=0; ct<4; ++ct){
        p0[ct] += __shfl_xor(p0[ct], 16);
        p0[ct] += __shfl_xor(p0[ct], 32);
        p1[ct] += __shfl_xor(p1[ct], 16);
        p1[ct] += __shfl_xor(p1[ct], 32);
    }
    if (g == 0){
        #pragma unroll
        for (int ct=0; ct<4; ++ct){
            int col = wv*64 + ct*16 + li;
            agg[(size_t)n0*H_ + col]     = p0[ct];
            agg[(size_t)(n0+1)*H_ + col] = p1[ct];
        }
    }
}

// ---------------- outputs ----------------
__global__ void k_out_x(const float* __restrict__ x, const float* __restrict__ x_in,
                        const float* __restrict__ nmask, float* __restrict__ out)
{
    int b = blockIdx.x; int l = threadIdx.x;
    int row = b*N_ + l;
    float xd0=0.f,xd1=0.f,xd2=0.f,nm=0.f;
    if (l < N_) {
        nm = nmask[row];
        xd0 = (x[(size_t)row*3+0]-x_in[(size_t)row*3+0])*nm;
        xd1 = (x[(size_t)row*3+1]-x_in[(size_t)row*3+1])*nm;
        xd2 = (x[(size_t)row*3+2]-x_in[(size_t)row*3+2])*nm;
    }
    float s0=xd0,s1=xd1,s2=xd2,sn=nm;
    #pragma unroll
    for (int off=32; off; off>>=1) {
        s0+=__shfl_xor(s0,off,64); s1+=__shfl_xor(s1,off,64);
        s2+=__shfl_xor(s2,off,64); sn+=__shfl_xor(sn,off,64);
    }
    float m0=s0/sn, m1=s1/sn, m2=s2/sn;
    if (l < N_) {
        out[(size_t)row*8+0]=(xd0-m0)*nm;
        out[(size_t)row*8+1]=(xd1-m1)*nm;
        out[(size_t)row*8+2]=(xd2-m2)*nm;
    }
}

__global__ void k_out_h(const float* __restrict__ h, const float* __restrict__ wout_w, const float* __restrict__ wout_b,
                        const float* __restrict__ nmask, float* __restrict__ out)
{
    int row = blockIdx.x; int lane = threadIdx.x;
    int c4 = lane<<2;
    float4 hv = *(const float4*)(h + (size_t)row*H_ + c4);
    float p0=0,p1=0,p2=0,p3=0,p4=0;
    float hvv[4] = {hv.x,hv.y,hv.z,hv.w};
    #pragma unroll
    for (int j=0;j<4;j++) {
        int k = c4+j;
        float hval = hvv[j];
        p0 += hval * wout_w[k*6+0];
        p1 += hval * wout_w[k*6+1];
        p2 += hval * wout_w[k*6+2];
        p3 += hval * wout_w[k*6+3];
        p4 += hval * wout_w[k*6+4];
    }
    #pragma unroll
    for (int off=32; off; off>>=1) {
        p0+=__shfl_xor(p0,off,64); p1+=__shfl_xor(p1,off,64); p2+=__shfl_xor(p2,off,64);
        p3+=__shfl_xor(p3,off,64); p4+=__shfl_xor(p4,off,64);
    }
    if (lane==0) {
        float nm = nmask[row];
        out[(size_t)row*8+3] = (p0+wout_b[0])*nm;
        out[(size_t)row*8+4] = (p1+wout_b[1])*nm;
        out[(size_t)row*8+5] = (p2+wout_b[2])*nm;
        out[(size_t)row*8+6] = (p3+wout_b[3])*nm;
        out[(size_t)row*8+7] = (p4+wout_b[4])*nm;
    }
}

extern "C" void kernel_launch(void* const* d_in, const int* in_sizes, int n_in,
                              void* d_out, int out_size, void* d_ws, size_t ws_size,
                              hipStream_t stream)
{
    const float* x_in  = (const float*)d_in[0];
    const float* h_in  = (const float*)d_in[1];
    const float* t     = (const float*)d_in[2];
    const float* nmask = (const float*)d_in[3];
    const float* emask = (const float*)d_in[4];
    const int*   eidx  = (const int*)d_in[5];
    const float* win_w = (const float*)d_in[6];
    const float* win_b = (const float*)d_in[7];
    const float* wout_w= (const float*)d_in[8];
    const float* wout_b= (const float*)d_in[9];
    const float* e_w1  = (const float*)d_in[10];
    const float* e_b1  = (const float*)d_in[11];
    const float* e_w2  = (const float*)d_in[12];
    const float* e_b2  = (const float*)d_in[13];
    const float* att_w = (const float*)d_in[14];
    const float* att_b = (const float*)d_in[15];
    const float* h_w1  = (const float*)d_in[16];
    const float* h_b1  = (const float*)d_in[17];
    const float* h_w2  = (const float*)d_in[18];
    const float* h_b2  = (const float*)d_in[19];
    const float* x_w1  = (const float*)d_in[20];
    const float* x_b1  = (const float*)d_in[21];
    const float* x_w2  = (const float*)d_in[22];
    const float* x_b2  = (const float*)d_in[23];
    const float* x_w3  = (const float*)d_in[24];
    float* out = (float*)d_out;

    char* ws = (char*)d_ws;
    size_t off = 0;
    auto alloc = [&](size_t bytes)->float* {
        float* p = (float*)(ws + off);
        off = (off + bytes + 255) & ~(size_t)255;
        return p;
    };
    float* h    = alloc((size_t)BN_*H_*4);
    float* xA   = alloc((size_t)BN_*3*4);
    float* xB   = alloc((size_t)BN_*3*4);
    float* a    = alloc((size_t)BE_*4);
    float* NB5  = alloc((size_t)5*BN_*H_*4);
    float* agg  = alloc((size_t)BN_*H_*4);
    float* hm1  = alloc((size_t)BN_*H_*4);
    // fragmentized W (bf16 hi/lo), all layers, both passes: L * 131072 ushorts each
    ushort* WfU = (ushort*)alloc((size_t)L_*131072*sizeof(ushort));
    ushort* WfM = (ushort*)alloc((size_t)L_*131072*sizeof(ushort));

    k_init_h<<<BN_, H_, 0, stream>>>(h_in, t, win_w, win_b, h);
    k_init_xa<<<(BE_+255)/256, 256, 0, stream>>>(x_in, eidx, emask, xA, a);
    k_wprep<<<(L_*2*8192+255)/256, 256, 0, stream>>>(x_w2, e_w2, WfU, WfM);

    float* x_cur = xA;
    float* x_new = xB;

    for (int l=0; l<L_; l++) {
        const float* xw1l = x_w1 + (size_t)l*514*H_;
        const float* ew1l = e_w1 + (size_t)l*514*H_;
        const float* hw1l = h_w1 + (size_t)l*512*H_;

        // 5 node-side GEMMs sharing A=h: XHi, XHj, EHi, EHj, Htop
        GArgs na = {};
        const float* Bz[5] = { xw1l, xw1l+(size_t)256*H_, ew1l, ew1l+(size_t)256*H_, hw1l };
        for (int z=0;z<5;z++){
            na.g[z].A=h; na.g[z].Bw=Bz[z]; na.g[z].bias=nullptr; na.g[z].add=nullptr;
            na.g[z].rmask=nullptr; na.g[z].C=NB5 + (size_t)z*BN_*H_;
        }
        k_gemm64<0><<<dim3(BN_/64, H_/64, 5),256,0,stream>>>(na, BN_, H_);

        float* XHi=NB5;
        float* XHj=NB5+(size_t)BN_*H_;
        float* EHi=NB5+(size_t)2*BN_*H_;
        float* EHj=NB5+(size_t)3*BN_*H_;
        float* Htop=NB5+(size_t)4*BN_*H_;

        // mega-fused edge pipeline: one block per node pair, no intermediates
        k_edge_mega<<<BN_/2, 256, 0, stream>>>(XHi, XHj, EHi, EHj, x_cur, a,
            eidx, emask, nmask,
            xw1l+(size_t)512*H_, xw1l+(size_t)513*H_, x_b1+(size_t)l*H_,
            ew1l+(size_t)512*H_, ew1l+(size_t)513*H_, e_b1+(size_t)l*H_,
            WfU + (size_t)l*131072, WfM + (size_t)l*131072,
            x_b2+(size_t)l*H_, x_w3+(size_t)l*H_,
            e_b2+(size_t)l*H_, att_w+(size_t)l*H_, att_b+l,
            x_new, agg);

        GArgs ha = {};
        ha.g[0] = { agg, hw1l+(size_t)256*H_, h_b1+(size_t)l*H_, Htop, nullptr, hm1 };
        k_gemm64<1><<<dim3(BN_/64,H_/64,1),256,0,stream>>>(ha, BN_, H_);

        GArgs h2 = {};
        h2.g[0] = { hm1, h_w2+(size_t)l*H_*H_, h_b2+(size_t)l*H_, h, nmask, h };
        k_gemm64<0><<<dim3(BN_/64,H_/64,1),256,0,stream>>>(h2, BN_, H_);

        float* tmp = x_cur; x_cur = x_new; x_new = tmp;
    }

    k_out_x<<<B_,64,0,stream>>>(x_cur, x_in, nmask, out);
    k_out_h<<<BN_,64,0,stream>>>(h, wout_w, wout_b, nmask, out);
}

// Round 10
// 1166.008 us; speedup vs baseline: 1.3524x; 1.0331x over previous
//
#include <hip/hip_runtime.h>
#include <math.h>

#define B_ 64
#define N_ 29
#define E_ 812
#define L_ 9
#define H_ 256
#define FA_ 5
#define BN_ (B_*N_)   // 1856
#define BE_ (B_*E_)   // 51968
#define DEG_ 28
#define SCALE_ 15.0f

typedef __attribute__((ext_vector_type(8))) short bf16x8;
typedef __attribute__((ext_vector_type(4))) float f32x4;

__device__ __forceinline__ float sigmoidf_(float v){ return 1.0f/(1.0f+expf(-v)); }
__device__ __forceinline__ float siluf_(float v){ return v/(1.0f+expf(-v)); }
// fast silu (edge path only): native exp + native rcp; ~5 ulp vs libm (proven safe R9)
__device__ __forceinline__ float fsilu_(float v){
    float e = __expf(-v);
    return v * __builtin_amdgcn_rcpf(1.0f + e);
}

// bf16 round-to-nearest-even conversion + back (exact RNE, proven path)
__device__ __forceinline__ ushort f2bf(float f){
    uint u = __float_as_uint(f);
    u += 0x7fffu + ((u>>16)&1u);
    return (ushort)(u>>16);
}
__device__ __forceinline__ float bf2f(ushort h){ return __uint_as_float(((uint)h)<<16); }

// ---------------- init ----------------
__global__ void k_init_h(const float* __restrict__ h_in, const float* __restrict__ t,
                         const float* __restrict__ win_w, const float* __restrict__ win_b,
                         float* __restrict__ h)
{
    int node = blockIdx.x; int c = threadIdx.x;
    float in[6];
    #pragma unroll
    for (int k=0;k<FA_;k++) in[k] = h_in[node*FA_+k];
    in[5] = t[node];
    float acc = win_b[c];
    #pragma unroll
    for (int k=0;k<6;k++) acc += in[k]*win_w[k*H_+c];
    h[(size_t)node*H_+c] = acc;
}

__global__ void k_init_xa(const float* __restrict__ x_in, const int* __restrict__ eidx,
                          const float* __restrict__ emask, float* __restrict__ x, float* __restrict__ a)
{
    int gid = blockIdx.x*256 + threadIdx.x;
    if (gid < BN_*3) x[gid] = x_in[gid];
    if (gid < BE_) {
        int b = gid / E_;
        int ii = eidx[2*gid], jj = eidx[2*gid+1];
        const float* xi = x_in + (size_t)(b*N_+ii)*3;
        const float* xj = x_in + (size_t)(b*N_+jj)*3;
        float dx = xi[0]-xj[0], dy = xi[1]-xj[1], dz = xi[2]-xj[2];
        a[gid] = sqrtf(dx*dx+dy*dy+dz*dz) * emask[gid];
    }
}

// ---------------- W fragmentization: row-major [K=256][N=256] fp32 -> MFMA B-frag bf16 hi/lo ----------------
// Layout per (layer,pass): hi plane [ks(8)][ct(16)][lane(64)][8] (65536 bf16), lo plane at +65536.
// Fragment semantic: lane holds B[k = ks*32 + (lane>>4)*8 + j][col = ct*16 + (lane&15)], j=0..7.
__global__ void k_wprep(const float* __restrict__ xw2, const float* __restrict__ ew2,
                        ushort* __restrict__ WfU, ushort* __restrict__ WfM)
{
    int gid = blockIdx.x*256 + threadIdx.x;
    if (gid >= L_*2*8192) return;
    int lane = gid & 63;
    int rest = gid >> 6;
    int ct = rest & 15; rest >>= 4;
    int ks = rest & 7;  rest >>= 3;
    int p  = rest & 1;  int l = rest >> 1;
    const float* src = (p ? ew2 : xw2) + (size_t)l*H_*H_;
    ushort* dst = (p ? WfM : WfU) + (size_t)l*131072;
    int g = lane>>4, li = lane&15;
    int col = ct*16 + li;
    int kb  = ks*32 + g*8;
    size_t fo = ((size_t)(ks*16+ct)*64 + lane)*8;
    ushort* dh = dst + fo;
    ushort* dl = dst + 65536 + fo;
    #pragma unroll
    for (int j=0;j<8;j++){
        float v = src[(size_t)(kb+j)*H_ + col];
        ushort h = f2bf(v);
        dh[j] = h;
        dl[j] = f2bf(v - bf2f(h));
    }
}

// ---------------- generic tiled fp32 GEMM (node-side) ----------------
struct GArg { const float* A; const float* Bw; const float* bias; const float* add; const float* rmask; float* C; };
struct GArgs { GArg g[6]; };

template<int ACT>
__global__ __launch_bounds__(256)
void k_gemm64(GArgs args, int M, int Kdim)
{
    const GArg ga = args.g[blockIdx.z];
    __shared__ float As[16*68];
    __shared__ float Bs[16*68];
    const int tid = threadIdx.x;
    const int row0 = blockIdx.x*64;
    const int col0 = blockIdx.y*64;
    const int ty = tid>>4, tx = tid&15;
    const int am = tid>>2, ak = (tid&3)<<2;
    const int bk = tid>>4, bn = (tid&15)<<2;
    float acc[4][4] = {};
    const float* Ap = ga.A + (size_t)min(row0+am, M-1)*Kdim + ak;
    const float* Bp = ga.Bw + (size_t)bk*H_ + col0 + bn;
    for (int k0=0; k0<Kdim; k0+=16) {
        float4 av = *(const float4*)(Ap + k0);
        float4 bv = *(const float4*)(Bp + (size_t)k0*H_);
        __syncthreads();
        As[(ak+0)*68+am]=av.x; As[(ak+1)*68+am]=av.y; As[(ak+2)*68+am]=av.z; As[(ak+3)*68+am]=av.w;
        *(float4*)&Bs[bk*68+bn] = bv;
        __syncthreads();
        #pragma unroll
        for (int k=0;k<16;k++) {
            float4 a4 = *(const float4*)&As[k*68 + (ty<<2)];
            float4 b4 = *(const float4*)&Bs[k*68 + (tx<<2)];
            float aa[4]={a4.x,a4.y,a4.z,a4.w};
            float bb[4]={b4.x,b4.y,b4.z,b4.w};
            #pragma unroll
            for (int i=0;i<4;i++)
                #pragma unroll
                for (int j=0;j<4;j++)
                    acc[i][j] = fmaf(aa[i], bb[j], acc[i][j]);
        }
    }
    const int r0 = row0 + (ty<<2);
    const int c0 = col0 + (tx<<2);
    float4 bias4 = make_float4(0.f,0.f,0.f,0.f);
    if (ga.bias) bias4 = *(const float4*)(ga.bias + c0);
    #pragma unroll
    for (int i=0;i<4;i++) {
        int r = r0+i;
        if (r >= M) break;
        float v0=acc[i][0]+bias4.x, v1=acc[i][1]+bias4.y, v2=acc[i][2]+bias4.z, v3=acc[i][3]+bias4.w;
        if (ga.add) {
            float4 ad = *(const float4*)(ga.add + (size_t)r*H_ + c0);
            v0+=ad.x; v1+=ad.y; v2+=ad.z; v3+=ad.w;
        }
        if (ACT==1) { v0=siluf_(v0); v1=siluf_(v1); v2=siluf_(v2); v3=siluf_(v3); }
        if (ga.rmask) { float mv = ga.rmask[r]; v0*=mv; v1*=mv; v2*=mv; v3*=mv; }
        *(float4*)(ga.C + (size_t)r*H_ + c0) = make_float4(v0,v1,v2,v3);
    }
}

// ---------------- in-LDS fragment compute (32-row band, one pass, 4 ks per thread) ----------------
// fragH/fragL layout: [ks(8)][rt(2)][lane(64)][8] ushorts (16 KB each).
// Thread (rt, ks0-half, lane) fills rows rt*16+(lane&15) for ks in [ks0, ks0+4).
__device__ __forceinline__ void frag_compute(
    const float* __restrict__ Xi, const float* __restrict__ Xj,
    const float* __restrict__ w5p, const float* __restrict__ w6p, const float* __restrict__ bp,
    int ni, int nj, float d2, float av, bool valid,
    int rt, int ks0, int lane,
    ushort (*fragH)[2][64][8], ushort (*fragL)[2][64][8])
{
    const int g = lane >> 4;
    if (valid){
        const float* xi = Xi + (size_t)ni*H_;
        const float* xj = Xj + (size_t)nj*H_;
        #pragma unroll
        for (int kq=0; kq<4; ++kq){
            int ks = ks0 + kq;
            int kb = ks*32 + g*8;
            float4 i0 = *(const float4*)(xi + kb),  i1 = *(const float4*)(xi + kb + 4);
            float4 j0 = *(const float4*)(xj + kb),  j1 = *(const float4*)(xj + kb + 4);
            float4 w50= *(const float4*)(w5p + kb), w51= *(const float4*)(w5p + kb + 4);
            float4 w60= *(const float4*)(w6p + kb), w61= *(const float4*)(w6p + kb + 4);
            float4 b0 = *(const float4*)(bp + kb),  b1v= *(const float4*)(bp + kb + 4);
            float v[8];
            v[0]=fsilu_(i0.x+j0.x+d2*w50.x+av*w60.x+b0.x);
            v[1]=fsilu_(i0.y+j0.y+d2*w50.y+av*w60.y+b0.y);
            v[2]=fsilu_(i0.z+j0.z+d2*w50.z+av*w60.z+b0.z);
            v[3]=fsilu_(i0.w+j0.w+d2*w50.w+av*w60.w+b0.w);
            v[4]=fsilu_(i1.x+j1.x+d2*w51.x+av*w61.x+b1v.x);
            v[5]=fsilu_(i1.y+j1.y+d2*w51.y+av*w61.y+b1v.y);
            v[6]=fsilu_(i1.z+j1.z+d2*w51.z+av*w61.z+b1v.z);
            v[7]=fsilu_(i1.w+j1.w+d2*w51.w+av*w61.w+b1v.w);
            ushort hh[8], ll[8];
            #pragma unroll
            for (int q=0;q<8;q++){ hh[q]=f2bf(v[q]); ll[q]=f2bf(v[q]-bf2f(hh[q])); }
            *(ushort4*)&fragH[ks][rt][lane][0] = make_ushort4(hh[0],hh[1],hh[2],hh[3]);
            *(ushort4*)&fragH[ks][rt][lane][4] = make_ushort4(hh[4],hh[5],hh[6],hh[7]);
            *(ushort4*)&fragL[ks][rt][lane][0] = make_ushort4(ll[0],ll[1],ll[2],ll[3]);
            *(ushort4*)&fragL[ks][rt][lane][4] = make_ushort4(ll[4],ll[5],ll[6],ll[7]);
        }
    } else {
        ushort4 z4 = make_ushort4(0,0,0,0);
        #pragma unroll
        for (int kq=0; kq<4; ++kq){
            int ks = ks0 + kq;
            *(ushort4*)&fragH[ks][rt][lane][0] = z4;
            *(ushort4*)&fragH[ks][rt][lane][4] = z4;
            *(ushort4*)&fragL[ks][rt][lane][0] = z4;
            *(ushort4*)&fragL[ks][rt][lane][4] = z4;
        }
    }
}

// ---------------- MFMA mainloop reading A-fragments from LDS (bf16x3, 32-row band) ----------------
__device__ __forceinline__ void mfma_lds(
    const ushort (*fragH)[2][64][8], const ushort (*fragL)[2][64][8],
    const ushort* __restrict__ bp, int lane, f32x4 (&acc)[2][4])
{
    #pragma unroll
    for (int ks=0; ks<8; ++ks){
        bf16x8 ah[2], al[2];
        #pragma unroll
        for (int rt=0; rt<2; ++rt){
            ah[rt] = *(const bf16x8*)&fragH[ks][rt][lane][0];
            al[rt] = *(const bf16x8*)&fragL[ks][rt][lane][0];
        }
        #pragma unroll
        for (int ct=0; ct<4; ++ct){
            bf16x8 bh = *(const bf16x8*)(bp + ks*8192 + ct*512);
            bf16x8 bl = *(const bf16x8*)(bp + 65536 + ks*8192 + ct*512);
            #pragma unroll
            for (int rt=0; rt<2; ++rt){
                acc[rt][ct] = __builtin_amdgcn_mfma_f32_16x16x32_bf16(ah[rt], bh, acc[rt][ct], 0,0,0);
                acc[rt][ct] = __builtin_amdgcn_mfma_f32_16x16x32_bf16(al[rt], bh, acc[rt][ct], 0,0,0);
                acc[rt][ct] = __builtin_amdgcn_mfma_f32_16x16x32_bf16(ah[rt], bl, acc[rt][ct], 0,0,0);
            }
        }
    }
}

// ---------------- mega-fused edge kernel: one NODE per block (28 edges padded to 32 rows) ----------------
// 4 waves: frag phase wave = (rt = wv&1, ks-half = wv>>1); GEMM phase wave = col quarter.
// LDS ~34 KB -> 4 blocks/CU (4 waves/SIMD), double R9's occupancy.
// Phases: u1 frags->LDS | U-GEMM (pdU) | m1 frags->LDS | M-GEMM (pdM, M2 in regs)
//         | per-edge scalars + x update (wave 0) | agg from regs.
__global__ __launch_bounds__(256, 4)
void k_edge_mega(const float* __restrict__ XHi, const float* __restrict__ XHj,
                 const float* __restrict__ EHi, const float* __restrict__ EHj,
                 const float* __restrict__ x_cur, const float* __restrict__ a,
                 const int* __restrict__ eidx, const float* __restrict__ emask,
                 const float* __restrict__ nmask,
                 const float* __restrict__ xw512, const float* __restrict__ xw513, const float* __restrict__ xb1,
                 const float* __restrict__ ew512, const float* __restrict__ ew513, const float* __restrict__ eb1,
                 const ushort* __restrict__ WfU, const ushort* __restrict__ WfM,
                 const float* __restrict__ xb2, const float* __restrict__ xw3,
                 const float* __restrict__ eb2, const float* __restrict__ attw,
                 const float* __restrict__ attb,
                 float* __restrict__ x_new, float* __restrict__ agg)
{
    __shared__ __align__(16) ushort fragH[8][2][64][8];   // 16 KB
    __shared__ __align__(16) ushort fragL[8][2][64][8];   // 16 KB
    __shared__ float pdLds[2][4][32];                     // 1 KB
    __shared__ float easLds[32];
    __shared__ float cxyz[DEG_][3];

    const int tid  = threadIdx.x;
    const int lane = tid & 63;
    const int wv   = tid >> 6;    // GEMM: col quarter; frag: (rt, ks-half)
    const int g    = lane >> 4;
    const int li   = lane & 15;
    const int rt   = wv & 1;      // frag row tile
    const int ks0  = (wv >> 1)*4; // frag ks half
    const int n0   = blockIdx.x;  // node (global row)

    // per-thread edge scalars for frag phases (row fixed per thread)
    const int frow = rt*16 + li;
    const bool valid = (frow < DEG_);
    int nj=0; float d2=0.f, av=0.f;
    if (valid){
        int bb = n0 / N_;
        size_t ge = (size_t)n0*DEG_ + frow;
        int jj = eidx[2*ge+1];
        nj = bb*N_ + jj;
        float em = emask[ge];
        float dx=(x_cur[n0*3+0]-x_cur[nj*3+0])*em;
        float dy=(x_cur[n0*3+1]-x_cur[nj*3+1])*em;
        float dz=(x_cur[n0*3+2]-x_cur[nj*3+2])*em;
        d2 = dx*dx+dy*dy+dz*dz;
        av = a[ge];
    }

    const ushort* bpU = WfU + ((size_t)(wv*4)*64 + lane)*8;
    const ushort* bpM = WfM + ((size_t)(wv*4)*64 + lane)*8;

    f32x4 acc[2][4];

    // ===== phase 1: u1 fragments -> LDS =====
    frag_compute(XHi, XHj, xw512, xw513, xb1, n0, nj, d2, av, valid, rt, ks0, lane, fragH, fragL);
    __syncthreads();

    // ===== phase 2: U-pass GEMM + pd epilogue =====
    #pragma unroll
    for (int r=0;r<2;++r)
        #pragma unroll
        for (int ct=0;ct<4;++ct)
            acc[r][ct] = (f32x4){0.f,0.f,0.f,0.f};
    mfma_lds(fragH, fragL, bpU, lane, acc);
    {
        float pdv[2][4];
        #pragma unroll
        for (int r=0;r<2;++r)
            #pragma unroll
            for (int rg=0;rg<4;++rg) pdv[r][rg]=0.f;
        #pragma unroll
        for (int ct=0; ct<4; ++ct){
            const int col = wv*64 + ct*16 + li;
            const float bi = xb2[col];
            const float wvv = xw3[col];
            #pragma unroll
            for (int r=0; r<2; ++r)
                #pragma unroll
                for (int rg=0; rg<4; ++rg)
                    pdv[r][rg] += fsilu_(acc[r][ct][rg] + bi)*wvv;
        }
        #pragma unroll
        for (int r=0;r<2;++r)
            #pragma unroll
            for (int rg=0;rg<4;++rg){
                float s = pdv[r][rg];
                s += __shfl_xor(s, 1, 16);
                s += __shfl_xor(s, 2, 16);
                s += __shfl_xor(s, 4, 16);
                s += __shfl_xor(s, 8, 16);
                if (li==0) pdLds[0][wv][r*16 + g*4 + rg] = s;
            }
    }
    __syncthreads();

    // ===== phase 3: m1 fragments -> LDS (overwrite) =====
    frag_compute(EHi, EHj, ew512, ew513, eb1, n0, nj, d2, av, valid, rt, ks0, lane, fragH, fragL);
    __syncthreads();

    // ===== phase 4: M-pass GEMM + pd epilogue (M2 stays in regs) =====
    #pragma unroll
    for (int r=0;r<2;++r)
        #pragma unroll
        for (int ct=0;ct<4;++ct)
            acc[r][ct] = (f32x4){0.f,0.f,0.f,0.f};
    mfma_lds(fragH, fragL, bpM, lane, acc);
    {
        float pdv[2][4];
        #pragma unroll
        for (int r=0;r<2;++r)
            #pragma unroll
            for (int rg=0;rg<4;++rg) pdv[r][rg]=0.f;
        #pragma unroll
        for (int ct=0; ct<4; ++ct){
            const int col = wv*64 + ct*16 + li;
            const float bi = eb2[col];
            const float wvv = attw[col];
            #pragma unroll
            for (int r=0; r<2; ++r)
                #pragma unroll
                for (int rg=0; rg<4; ++rg){
                    float v = fsilu_(acc[r][ct][rg] + bi);
                    acc[r][ct][rg] = v;          // keep silu'd M2 value for agg
                    pdv[r][rg] += v*wvv;
                }
        }
        #pragma unroll
        for (int r=0;r<2;++r)
            #pragma unroll
            for (int rg=0;rg<4;++rg){
                float s = pdv[r][rg];
                s += __shfl_xor(s, 1, 16);
                s += __shfl_xor(s, 2, 16);
                s += __shfl_xor(s, 4, 16);
                s += __shfl_xor(s, 8, 16);
                if (li==0) pdLds[1][wv][r*16 + g*4 + rg] = s;
            }
    }
    __syncthreads();

    // ===== phase 5: per-edge scalars + x update (wave 0) =====
    if (wv == 0){
        int t = lane;
        if (t < 32){
            float ea = 0.f;
            if (t < DEG_){
                float sU = pdLds[0][0][t]+pdLds[0][1][t]+pdLds[0][2][t]+pdLds[0][3][t];
                float sM = pdLds[1][0][t]+pdLds[1][1][t]+pdLds[1][2][t]+pdLds[1][3][t];
                float tsc = tanhf(sU)*SCALE_;
                ea = sigmoidf_(sM + attb[0]);
                size_t ge = (size_t)n0*DEG_ + t;
                int bb = n0 / N_;
                int jj = eidx[2*ge+1];
                int njs = bb*N_ + jj;
                float em = emask[ge];
                float dx=(x_cur[n0*3+0]-x_cur[njs*3+0])*em;
                float dy=(x_cur[n0*3+1]-x_cur[njs*3+1])*em;
                float dz=(x_cur[n0*3+2]-x_cur[njs*3+2])*em;
                float dd = sqrtf(dx*dx+dy*dy+dz*dz);
                float sc = tsc/(dd+1.0f);
                cxyz[t][0]=sc*dx; cxyz[t][1]=sc*dy; cxyz[t][2]=sc*dz;
            }
            easLds[t] = ea;
        }
        if (t == 0){
            float sx=0.f, sy=0.f, sz=0.f;
            #pragma unroll 4
            for (int k=0;k<DEG_;k++){ sx+=cxyz[k][0]; sy+=cxyz[k][1]; sz+=cxyz[k][2]; }
            float nm = nmask[n0];
            x_new[n0*3+0]=(x_cur[n0*3+0]+sx)*nm;
            x_new[n0*3+1]=(x_cur[n0*3+1]+sy)*nm;
            x_new[n0*3+2]=(x_cur[n0*3+2]+sz)*nm;
        }
    }
    __syncthreads();

    // ===== phase 6: agg from register-resident M2 =====
    float p[4] = {0.f,0.f,0.f,0.f};
    #pragma unroll
    for (int r=0; r<2; ++r){
        #pragma unroll
        for (int rg=0; rg<4; ++rg){
            int row = r*16 + g*4 + rg;
            float w = easLds[row];
            #pragma unroll
            for (int ct=0; ct<4; ++ct)
                p[ct] += w*acc[r][ct][rg];
        }
    }
    #pragma unroll
    for (int ct=0; ct<4; ++ct){
        p[ct] += __shfl_xor(p[ct], 16);
        p[ct] += __shfl_xor(p[ct], 32);
    }
    if (g == 0){
        #pragma unroll
        for (int ct=0; ct<4; ++ct){
            int col = wv*64 + ct*16 + li;
            agg[(size_t)n0*H_ + col] = p[ct];
        }
    }
}

// ---------------- outputs ----------------
__global__ void k_out_x(const float* __restrict__ x, const float* __restrict__ x_in,
                        const float* __restrict__ nmask, float* __restrict__ out)
{
    int b = blockIdx.x; int l = threadIdx.x;
    int row = b*N_ + l;
    float xd0=0.f,xd1=0.f,xd2=0.f,nm=0.f;
    if (l < N_) {
        nm = nmask[row];
        xd0 = (x[(size_t)row*3+0]-x_in[(size_t)row*3+0])*nm;
        xd1 = (x[(size_t)row*3+1]-x_in[(size_t)row*3+1])*nm;
        xd2 = (x[(size_t)row*3+2]-x_in[(size_t)row*3+2])*nm;
    }
    float s0=xd0,s1=xd1,s2=xd2,sn=nm;
    #pragma unroll
    for (int off=32; off; off>>=1) {
        s0+=__shfl_xor(s0,off,64); s1+=__shfl_xor(s1,off,64);
        s2+=__shfl_xor(s2,off,64); sn+=__shfl_xor(sn,off,64);
    }
    float m0=s0/sn, m1=s1/sn, m2=s2/sn;
    if (l < N_) {
        out[(size_t)row*8+0]=(xd0-m0)*nm;
        out[(size_t)row*8+1]=(xd1-m1)*nm;
        out[(size_t)row*8+2]=(xd2-m2)*nm;
    }
}

__global__ void k_out_h(const float* __restrict__ h, const float* __restrict__ wout_w, const float* __restrict__ wout_b,
                        const float* __restrict__ nmask, float* __restrict__ out)
{
    int row = blockIdx.x; int lane = threadIdx.x;
    int c4 = lane<<2;
    float4 hv = *(const float4*)(h + (size_t)row*H_ + c4);
    float p0=0,p1=0,p2=0,p3=0,p4=0;
    float hvv[4] = {hv.x,hv.y,hv.z,hv.w};
    #pragma unroll
    for (int j=0;j<4;j++) {
        int k = c4+j;
        float hval = hvv[j];
        p0 += hval * wout_w[k*6+0];
        p1 += hval * wout_w[k*6+1];
        p2 += hval * wout_w[k*6+2];
        p3 += hval * wout_w[k*6+3];
        p4 += hval * wout_w[k*6+4];
    }
    #pragma unroll
    for (int off=32; off; off>>=1) {
        p0+=__shfl_xor(p0,off,64); p1+=__shfl_xor(p1,off,64); p2+=__shfl_xor(p2,off,64);
        p3+=__shfl_xor(p3,off,64); p4+=__shfl_xor(p4,off,64);
    }
    if (lane==0) {
        float nm = nmask[row];
        out[(size_t)row*8+3] = (p0+wout_b[0])*nm;
        out[(size_t)row*8+4] = (p1+wout_b[1])*nm;
        out[(size_t)row*8+5] = (p2+wout_b[2])*nm;
        out[(size_t)row*8+6] = (p3+wout_b[3])*nm;
        out[(size_t)row*8+7] = (p4+wout_b[4])*nm;
    }
}

extern "C" void kernel_launch(void* const* d_in, const int* in_sizes, int n_in,
                              void* d_out, int out_size, void* d_ws, size_t ws_size,
                              hipStream_t stream)
{
    const float* x_in  = (const float*)d_in[0];
    const float* h_in  = (const float*)d_in[1];
    const float* t     = (const float*)d_in[2];
    const float* nmask = (const float*)d_in[3];
    const float* emask = (const float*)d_in[4];
    const int*   eidx  = (const int*)d_in[5];
    const float* win_w = (const float*)d_in[6];
    const float* win_b = (const float*)d_in[7];
    const float* wout_w= (const float*)d_in[8];
    const float* wout_b= (const float*)d_in[9];
    const float* e_w1  = (const float*)d_in[10];
    const float* e_b1  = (const float*)d_in[11];
    const float* e_w2  = (const float*)d_in[12];
    const float* e_b2  = (const float*)d_in[13];
    const float* att_w = (const float*)d_in[14];
    const float* att_b = (const float*)d_in[15];
    const float* h_w1  = (const float*)d_in[16];
    const float* h_b1  = (const float*)d_in[17];
    const float* h_w2  = (const float*)d_in[18];
    const float* h_b2  = (const float*)d_in[19];
    const float* x_w1  = (const float*)d_in[20];
    const float* x_b1  = (const float*)d_in[21];
    const float* x_w2  = (const float*)d_in[22];
    const float* x_b2  = (const float*)d_in[23];
    const float* x_w3  = (const float*)d_in[24];
    float* out = (float*)d_out;

    char* ws = (char*)d_ws;
    size_t off = 0;
    auto alloc = [&](size_t bytes)->float* {
        float* p = (float*)(ws + off);
        off = (off + bytes + 255) & ~(size_t)255;
        return p;
    };
    float* h    = alloc((size_t)BN_*H_*4);
    float* xA   = alloc((size_t)BN_*3*4);
    float* xB   = alloc((size_t)BN_*3*4);
    float* a    = alloc((size_t)BE_*4);
    float* NB5  = alloc((size_t)5*BN_*H_*4);
    float* agg  = alloc((size_t)BN_*H_*4);
    float* hm1  = alloc((size_t)BN_*H_*4);
    // fragmentized W (bf16 hi/lo), all layers, both passes: L * 131072 ushorts each
    ushort* WfU = (ushort*)alloc((size_t)L_*131072*sizeof(ushort));
    ushort* WfM = (ushort*)alloc((size_t)L_*131072*sizeof(ushort));

    k_init_h<<<BN_, H_, 0, stream>>>(h_in, t, win_w, win_b, h);
    k_init_xa<<<(BE_+255)/256, 256, 0, stream>>>(x_in, eidx, emask, xA, a);
    k_wprep<<<(L_*2*8192+255)/256, 256, 0, stream>>>(x_w2, e_w2, WfU, WfM);

    float* x_cur = xA;
    float* x_new = xB;

    for (int l=0; l<L_; l++) {
        const float* xw1l = x_w1 + (size_t)l*514*H_;
        const float* ew1l = e_w1 + (size_t)l*514*H_;
        const float* hw1l = h_w1 + (size_t)l*512*H_;

        // 5 node-side GEMMs sharing A=h: XHi, XHj, EHi, EHj, Htop
        GArgs na = {};
        const float* Bz[5] = { xw1l, xw1l+(size_t)256*H_, ew1l, ew1l+(size_t)256*H_, hw1l };
        for (int z=0;z<5;z++){
            na.g[z].A=h; na.g[z].Bw=Bz[z]; na.g[z].bias=nullptr; na.g[z].add=nullptr;
            na.g[z].rmask=nullptr; na.g[z].C=NB5 + (size_t)z*BN_*H_;
        }
        k_gemm64<0><<<dim3(BN_/64, H_/64, 5),256,0,stream>>>(na, BN_, H_);

        float* XHi=NB5;
        float* XHj=NB5+(size_t)BN_*H_;
        float* EHi=NB5+(size_t)2*BN_*H_;
        float* EHj=NB5+(size_t)3*BN_*H_;
        float* Htop=NB5+(size_t)4*BN_*H_;

        // mega-fused edge pipeline: one block per NODE, no intermediates
        k_edge_mega<<<BN_, 256, 0, stream>>>(XHi, XHj, EHi, EHj, x_cur, a,
            eidx, emask, nmask,
            xw1l+(size_t)512*H_, xw1l+(size_t)513*H_, x_b1+(size_t)l*H_,
            ew1l+(size_t)512*H_, ew1l+(size_t)513*H_, e_b1+(size_t)l*H_,
            WfU + (size_t)l*131072, WfM + (size_t)l*131072,
            x_b2+(size_t)l*H_, x_w3+(size_t)l*H_,
            e_b2+(size_t)l*H_, att_w+(size_t)l*H_, att_b+l,
            x_new, agg);

        GArgs ha = {};
        ha.g[0] = { agg, hw1l+(size_t)256*H_, h_b1+(size_t)l*H_, Htop, nullptr, hm1 };
        k_gemm64<1><<<dim3(BN_/64,H_/64,1),256,0,stream>>>(ha, BN_, H_);

        GArgs h2 = {};
        h2.g[0] = { hm1, h_w2+(size_t)l*H_*H_, h_b2+(size_t)l*H_, h, nmask, h };
        k_gemm64<0><<<dim3(BN_/64,H_/64,1),256,0,stream>>>(h2, BN_, H_);

        float* tmp = x_cur; x_cur = x_new; x_new = tmp;
    }

    k_out_x<<<B_,64,0,stream>>>(x_cur, x_in, nmask, out);
    k_out_h<<<BN_,64,0,stream>>>(h, wout_w, wout_b, nmask, out);
}